// Round 1
// baseline (1109.138 us; speedup 1.0000x reference)
//
#include <hip/hip_runtime.h>
#include <math.h>

#define SEQ 2516
#define CDIM 128

__device__ __forceinline__ float gelu_exact(float x) {
    return x * 0.5f * (1.0f + erff(x * 0.7071067811865475f));
}

// ---------------- build x = concat(task_descriptor, support.transpose(0,2,3,1)) ----
__global__ __launch_bounds__(256) void concat_kernel(
    const float* __restrict__ td, const float* __restrict__ sup, float* __restrict__ X) {
    int i = blockIdx.x * 256 + threadIdx.x;
    if (i >= SEQ * CDIM) return;
    int row = i >> 7, c = i & 127;
    if (row < 16) {
        X[i] = td[i];
    } else {
        int r = row - 16;
        int n = r / 100, p = r - n * 100;
        X[i] = sup[n * 12800 + c * 100 + p];
    }
}

// ---------------- row layernorm over last dim (128), 1 wave per row -------------
__global__ __launch_bounds__(64) void ln_row_kernel(
    const float* __restrict__ in, float* __restrict__ out,
    const float* __restrict__ g, const float* __restrict__ b, float eps) {
    const int row = blockIdx.x;
    const int t = threadIdx.x;
    float x0 = in[row * 128 + t];
    float x1 = in[row * 128 + 64 + t];
    float s = x0 + x1;
    for (int off = 32; off > 0; off >>= 1) s += __shfl_down(s, off);
    float mean = __shfl(s, 0) * (1.f / 128.f);
    float d0 = x0 - mean, d1 = x1 - mean;
    float v = d0 * d0 + d1 * d1;
    for (int off = 32; off > 0; off >>= 1) v += __shfl_down(v, off);
    float var = __shfl(v, 0) * (1.f / 128.f);
    float rstd = rsqrtf(var + eps);
    out[row * 128 + t]      = d0 * rstd * g[t] + b[t];
    out[row * 128 + 64 + t] = d1 * rstd * g[t + 64] + b[t + 64];
}

// ---------------- tiled fp32 GEMM: C = act(A@W + bias) (+ R) --------------------
// A: MxK row-major, W: KxN row-major. BLK 64x64x16, 256 thr, 4x4 microtile.
// ACT: 0=none, 1=gelu. RES: add R elementwise.
template<int ACT, bool RES>
__global__ __launch_bounds__(256) void gemm_kernel(
    const float* __restrict__ A, const float* __restrict__ W,
    const float* __restrict__ bias, const float* __restrict__ R,
    float* __restrict__ C, int M, int N, int K) {
    __shared__ float As[16][65];
    __shared__ float Bs[16][64];
    const int tid = threadIdx.x;
    const int tx = tid & 15, ty = tid >> 4;
    const int m0 = blockIdx.y * 64, n0 = blockIdx.x * 64;
    const int am = tid >> 2;          // 0..63 (row within A tile)
    const int ak = (tid & 3) << 2;    // 0,4,8,12
    const int bk = tid >> 4;          // 0..15
    const int bn = (tid & 15) << 2;   // 0..60
    float acc[4][4] = {{0.f}};
    for (int k0 = 0; k0 < K; k0 += 16) {
        float4 av = make_float4(0.f, 0.f, 0.f, 0.f);
        if (m0 + am < M) av = *(const float4*)&A[(size_t)(m0 + am) * K + k0 + ak];
        As[ak + 0][am] = av.x; As[ak + 1][am] = av.y;
        As[ak + 2][am] = av.z; As[ak + 3][am] = av.w;
        *(float4*)&Bs[bk][bn] = *(const float4*)&W[(size_t)(k0 + bk) * N + n0 + bn];
        __syncthreads();
        #pragma unroll
        for (int k = 0; k < 16; ++k) {
            float a0 = As[k][ty * 4 + 0], a1 = As[k][ty * 4 + 1];
            float a2 = As[k][ty * 4 + 2], a3 = As[k][ty * 4 + 3];
            float4 bv = *(const float4*)&Bs[k][tx * 4];
            acc[0][0] += a0 * bv.x; acc[0][1] += a0 * bv.y; acc[0][2] += a0 * bv.z; acc[0][3] += a0 * bv.w;
            acc[1][0] += a1 * bv.x; acc[1][1] += a1 * bv.y; acc[1][2] += a1 * bv.z; acc[1][3] += a1 * bv.w;
            acc[2][0] += a2 * bv.x; acc[2][1] += a2 * bv.y; acc[2][2] += a2 * bv.z; acc[2][3] += a2 * bv.w;
            acc[3][0] += a3 * bv.x; acc[3][1] += a3 * bv.y; acc[3][2] += a3 * bv.z; acc[3][3] += a3 * bv.w;
        }
        __syncthreads();
    }
    const int nn0 = n0 + tx * 4;
    float4 bias4 = *(const float4*)&bias[nn0];
    #pragma unroll
    for (int i = 0; i < 4; ++i) {
        int mm = m0 + ty * 4 + i;
        if (mm >= M) continue;
        float4 res;
        res.x = acc[i][0] + bias4.x; res.y = acc[i][1] + bias4.y;
        res.z = acc[i][2] + bias4.z; res.w = acc[i][3] + bias4.w;
        if (ACT == 1) {
            res.x = gelu_exact(res.x); res.y = gelu_exact(res.y);
            res.z = gelu_exact(res.z); res.w = gelu_exact(res.w);
        }
        if (RES) {
            float4 r4 = *(const float4*)&R[(size_t)mm * N + nn0];
            res.x += r4.x; res.y += r4.y; res.z += r4.z; res.w += r4.w;
        }
        *(float4*)&C[(size_t)mm * N + nn0] = res;
    }
}

// ---------------- attention: flash-style, fp32, dh=16, 8 heads ------------------
// grid (ceil(SEQ/64), 8 heads), block 256. Thread t: query row = blk*64 + (t&63),
// key chunk = t>>6 (4-way split). K/V tiles of 256 rows staged in LDS.
__global__ __launch_bounds__(256) void attn_kernel(
    const float* __restrict__ qkv, float* __restrict__ O) {
    __shared__ float Ks[256 * 16];
    __shared__ float Vs[256 * 16];
    const int t = threadIdx.x;
    const int rl = t & 63;
    const int chunk = t >> 6;
    const int head = blockIdx.y;
    const int qrow = blockIdx.x * 64 + rl;
    float q[16];
    #pragma unroll
    for (int d = 0; d < 16; ++d)
        q[d] = (qrow < SEQ) ? qkv[(size_t)qrow * 384 + head * 16 + d] : 0.f;
    float m = -INFINITY, l = 0.f;
    float acc[16];
    #pragma unroll
    for (int d = 0; d < 16; ++d) acc[d] = 0.f;

    for (int tile0 = 0; tile0 < SEQ; tile0 += 256) {
        int j = tile0 + t;
        if (j < SEQ) {
            const float* kp = &qkv[(size_t)j * 384 + 128 + head * 16];
            const float* vp = &qkv[(size_t)j * 384 + 256 + head * 16];
            #pragma unroll
            for (int d = 0; d < 16; ++d) { Ks[t * 16 + d] = kp[d]; Vs[t * 16 + d] = vp[d]; }
        }
        __syncthreads();
        int nkeys = SEQ - tile0; if (nkeys > 256) nkeys = 256;
        int base = chunk * 64;
        int cnt = nkeys - base; if (cnt > 64) cnt = 64;
        for (int jj = 0; jj < cnt; ++jj) {
            const float* kr = &Ks[(base + jj) * 16];
            float s = 0.f;
            #pragma unroll
            for (int d = 0; d < 16; ++d) s += q[d] * kr[d];
            s *= 0.25f;                       // 1/sqrt(16)
            float nm = fmaxf(m, s);
            float corr = expf(m - nm);        // m=-inf -> 0, safe
            float e = expf(s - nm);
            l = l * corr + e;
            const float* vr = &Vs[(base + jj) * 16];
            #pragma unroll
            for (int d = 0; d < 16; ++d) acc[d] = acc[d] * corr + e * vr[d];
            m = nm;
        }
        __syncthreads();
    }
    // combine 4 chunks per row via LDS (reuse Ks/Vs)
    float* pacc = Ks;            // 256*16
    float* pm = Vs;              // 256
    float* pl = Vs + 256;        // 256
    #pragma unroll
    for (int d = 0; d < 16; ++d) pacc[t * 16 + d] = acc[d];
    pm[t] = m; pl[t] = l;
    __syncthreads();
    if (t < 64) {
        int row = blockIdx.x * 64 + t;
        if (row < SEQ) {
            float M = -INFINITY;
            #pragma unroll
            for (int c = 0; c < 4; ++c) M = fmaxf(M, pm[c * 64 + t]);
            float L = 0.f;
            float o[16];
            #pragma unroll
            for (int d = 0; d < 16; ++d) o[d] = 0.f;
            #pragma unroll
            for (int c = 0; c < 4; ++c) {
                float w = expf(pm[c * 64 + t] - M);
                L += pl[c * 64 + t] * w;
                const float* pa = &pacc[(c * 64 + t) * 16];
                #pragma unroll
                for (int d = 0; d < 16; ++d) o[d] += pa[d] * w;
            }
            float inv = 1.f / L;
            #pragma unroll
            for (int d = 0; d < 16; ++d)
                O[(size_t)row * 128 + head * 16 + d] = o[d] * inv;
        }
    }
}

// ---------------- region + map_fuse: fused = feat * (mean_m sigmoid(feat.key0/128)+1)
__global__ __launch_bounds__(256) void region_fuse_kernel(
    const float* __restrict__ sup, const float* __restrict__ qry,
    const float* __restrict__ X, float* __restrict__ fused) {
    __shared__ float key0[2048];   // 16 x 128
    __shared__ float rfac[100];
    const int b = blockIdx.x;
    const int t = threadIdx.x;
    const float* feat = (b < 25) ? (sup + (size_t)b * 12800) : (qry + (size_t)(b - 25) * 12800);
    for (int i = t; i < 2048; i += 256) key0[i] = X[i];
    __syncthreads();
    if (t < 100) {
        float dots[16];
        #pragma unroll
        for (int mm = 0; mm < 16; ++mm) dots[mm] = 0.f;
        for (int c = 0; c < 128; ++c) {
            float f = feat[c * 100 + t];
            #pragma unroll
            for (int mm = 0; mm < 16; ++mm) dots[mm] += f * key0[mm * 128 + c];
        }
        float mean = 0.f;
        #pragma unroll
        for (int mm = 0; mm < 16; ++mm) mean += 1.f / (1.f + expf(-dots[mm] * (1.f / 128.f)));
        rfac[t] = mean * (1.f / 16.f) + 1.f;
    }
    __syncthreads();
    for (int i = t; i < 12800; i += 256)
        fused[(size_t)b * 12800 + i] = feat[i] * rfac[i % 100];
}

// ---------------- channel layernorm per (b, spatial-pos): mean/var over 128 ch ---
__global__ __launch_bounds__(64) void ln_chan_kernel(
    const float* __restrict__ in, float* __restrict__ out,
    const float* __restrict__ g, const float* __restrict__ bb) {
    const int bp = blockIdx.x;
    const int b = bp / 100, p = bp - b * 100;
    const int t = threadIdx.x;
    const float* base = in + (size_t)b * 12800 + p;
    float x0 = base[t * 100];
    float x1 = base[(t + 64) * 100];
    float s = x0 + x1;
    for (int off = 32; off > 0; off >>= 1) s += __shfl_down(s, off);
    float mean = __shfl(s, 0) * (1.f / 128.f);
    float d0 = x0 - mean, d1 = x1 - mean;
    float v = d0 * d0 + d1 * d1;
    for (int off = 32; off > 0; off >>= 1) v += __shfl_down(v, off);
    float var = __shfl(v, 0) * (1.f / 128.f);
    float rstd = rsqrtf(var + 1e-6f);
    out[(size_t)b * 12800 + t * 100 + p]        = d0 * rstd * g[t] + bb[t];
    out[(size_t)b * 12800 + (t + 64) * 100 + p] = d1 * rstd * g[t + 64] + bb[t + 64];
}

// ---------------- 3x3 conv, pad 1, 10x10 images, input staged in LDS ------------
template<int CIN, bool RELU>
__global__ __launch_bounds__(256) void conv3x3_kernel(
    const float* __restrict__ in, const float* __restrict__ w, float* __restrict__ out) {
    __shared__ float sin_[CIN * 100];
    const int b = blockIdx.x;
    const int t = threadIdx.x;
    for (int i = t; i < CIN * 100; i += 256) sin_[i] = in[(size_t)b * CIN * 100 + i];
    __syncthreads();
    for (int o = t; o < 3200; o += 256) {
        int to = o / 100, p = o - to * 100;
        int y = p / 10, x = p - y * 10;
        const float* wp = w + (size_t)to * CIN * 9;
        float acc = 0.f;
        #pragma unroll
        for (int dy = 0; dy < 3; ++dy) {
            int yy = y + dy - 1;
            if ((unsigned)yy >= 10u) continue;
            #pragma unroll
            for (int dx = 0; dx < 3; ++dx) {
                int xx = x + dx - 1;
                if ((unsigned)xx >= 10u) continue;
                const float* sp = sin_ + yy * 10 + xx;
                const float* wq = wp + dy * 3 + dx;
                #pragma unroll 8
                for (int c = 0; c < CIN; ++c) acc += sp[c * 100] * wq[c * 9];
            }
        }
        if (RELU) acc = fmaxf(acc, 0.f);
        out[(size_t)b * 3200 + o] = acc;
    }
}

// ---------------- final pooling: out[b,c,t] = (1/100) sum_p sigmoid(conv4)*fused -
__global__ __launch_bounds__(256) void rfm_out_kernel(
    const float* __restrict__ conv4, const float* __restrict__ fused, float* __restrict__ out) {
    __shared__ float sig[3200];
    __shared__ float sf[12800];
    const int b = blockIdx.x;
    const int t = threadIdx.x;
    for (int i = t; i < 3200; i += 256) sig[i] = 1.f / (1.f + expf(-conv4[(size_t)b * 3200 + i]));
    for (int i = t; i < 12800; i += 256) sf[i] = fused[(size_t)b * 12800 + i];
    __syncthreads();
    for (int o = t; o < 4096; o += 256) {
        int c = o >> 5, tt = o & 31;
        float acc = 0.f;
        for (int p = 0; p < 100; ++p) acc += sig[tt * 100 + p] * sf[c * 100 + p];
        out[(size_t)b * 4096 + o] = acc * 0.01f;   // o == c*32 + tt
    }
}

extern "C" void kernel_launch(void* const* d_in, const int* in_sizes, int n_in,
                              void* d_out, int out_size, void* d_ws, size_t ws_size,
                              hipStream_t stream) {
    (void)in_sizes; (void)n_in; (void)out_size; (void)ws_size;
    const float* sup    = (const float*)d_in[0];
    const float* qry    = (const float*)d_in[1];
    const float* td     = (const float*)d_in[2];
    const float* ln1_g  = (const float*)d_in[3];
    const float* ln1_b  = (const float*)d_in[4];
    const float* qkv_w  = (const float*)d_in[5];
    const float* qkv_b  = (const float*)d_in[6];
    const float* out_w  = (const float*)d_in[7];
    const float* out_b  = (const float*)d_in[8];
    const float* ln2_g  = (const float*)d_in[9];
    const float* ln2_b  = (const float*)d_in[10];
    const float* mlp_w1 = (const float*)d_in[11];
    const float* mlp_b1 = (const float*)d_in[12];
    const float* mlp_w2 = (const float*)d_in[13];
    const float* mlp_b2 = (const float*)d_in[14];
    const float* rg     = (const float*)d_in[15];
    const float* rb     = (const float*)d_in[16];
    const float* c1     = (const float*)d_in[17];
    const float* c2     = (const float*)d_in[18];
    const float* c3     = (const float*)d_in[19];
    const float* c4     = (const float*)d_in[20];
    float* out = (float*)d_out;

    float* ws   = (float*)d_ws;
    float* X    = ws;                  // 2516*128 = 322048
    float* H    = X + 322048;          // 322048
    float* QKV  = H + 322048;          // 2516*384 = 966144
    float* Obuf = QKV + 966144;        // 322048
    float* MLPH = Obuf + 322048;       // 2516*512 = 1288192
    float* FUSED= MLPH + 1288192;      // 100*128*100 = 1280000
    float* LNO  = FUSED + 1280000;     // 1280000
    float* CB1  = LNO + 1280000;       // 100*32*100 = 320000
    float* CB2  = CB1 + 320000;        // 320000
    // total: 6,420,480 floats = 25.7 MB of ws

    concat_kernel<<<(SEQ * CDIM + 255) / 256, 256, 0, stream>>>(td, sup, X);
    for (int i = 0; i < 2; ++i) {
        ln_row_kernel<<<SEQ, 64, 0, stream>>>(X, H, ln1_g + i * 128, ln1_b + i * 128, 1e-5f);
        gemm_kernel<0, false><<<dim3(6, 40), 256, 0, stream>>>(
            H, qkv_w + (size_t)i * 128 * 384, qkv_b + i * 384, nullptr, QKV, SEQ, 384, 128);
        attn_kernel<<<dim3(40, 8), 256, 0, stream>>>(QKV, Obuf);
        gemm_kernel<0, true><<<dim3(2, 40), 256, 0, stream>>>(
            Obuf, out_w + (size_t)i * 128 * 128, out_b + i * 128, X, X, SEQ, 128, 128);
        ln_row_kernel<<<SEQ, 64, 0, stream>>>(X, H, ln2_g + i * 128, ln2_b + i * 128, 1e-5f);
        gemm_kernel<1, false><<<dim3(8, 40), 256, 0, stream>>>(
            H, mlp_w1 + (size_t)i * 128 * 512, mlp_b1 + i * 512, nullptr, MLPH, SEQ, 512, 128);
        gemm_kernel<0, true><<<dim3(2, 40), 256, 0, stream>>>(
            MLPH, mlp_w2 + (size_t)i * 512 * 128, mlp_b2 + i * 128, X, X, SEQ, 128, 512);
    }
    region_fuse_kernel<<<100, 256, 0, stream>>>(sup, qry, X, FUSED);
    ln_chan_kernel<<<10000, 64, 0, stream>>>(FUSED, LNO, rg, rb);
    conv3x3_kernel<128, true ><<<100, 256, 0, stream>>>(LNO, c1, CB1);
    conv3x3_kernel< 32, true ><<<100, 256, 0, stream>>>(CB1, c2, CB2);
    conv3x3_kernel< 32, true ><<<100, 256, 0, stream>>>(CB2, c3, CB1);
    conv3x3_kernel< 32, false><<<100, 256, 0, stream>>>(CB1, c4, CB2);
    rfm_out_kernel<<<100, 256, 0, stream>>>(CB2, FUSED, out);
}

// Round 2
// 812.342 us; speedup vs baseline: 1.3654x; 1.3654x over previous
//
#include <hip/hip_runtime.h>
#include <math.h>

#define SEQ 2516
#define CDIM 128

__device__ __forceinline__ float gelu_exact(float x) {
    return x * 0.5f * (1.0f + erff(x * 0.7071067811865475f));
}

// ---------------- build x = concat(task_descriptor, support.transpose(0,2,3,1)) ----
__global__ __launch_bounds__(256) void concat_kernel(
    const float* __restrict__ td, const float* __restrict__ sup, float* __restrict__ X) {
    int i = blockIdx.x * 256 + threadIdx.x;
    if (i >= SEQ * CDIM) return;
    int row = i >> 7, c = i & 127;
    if (row < 16) {
        X[i] = td[i];
    } else {
        int r = row - 16;
        int n = r / 100, p = r - n * 100;
        X[i] = sup[n * 12800 + c * 100 + p];
    }
}

// ---------------- row layernorm over last dim (128), 1 wave per row -------------
__global__ __launch_bounds__(64) void ln_row_kernel(
    const float* __restrict__ in, float* __restrict__ out,
    const float* __restrict__ g, const float* __restrict__ b, float eps) {
    const int row = blockIdx.x;
    const int t = threadIdx.x;
    float x0 = in[row * 128 + t];
    float x1 = in[row * 128 + 64 + t];
    float s = x0 + x1;
    for (int off = 32; off > 0; off >>= 1) s += __shfl_down(s, off);
    float mean = __shfl(s, 0) * (1.f / 128.f);
    float d0 = x0 - mean, d1 = x1 - mean;
    float v = d0 * d0 + d1 * d1;
    for (int off = 32; off > 0; off >>= 1) v += __shfl_down(v, off);
    float var = __shfl(v, 0) * (1.f / 128.f);
    float rstd = rsqrtf(var + eps);
    out[row * 128 + t]      = d0 * rstd * g[t] + b[t];
    out[row * 128 + 64 + t] = d1 * rstd * g[t + 64] + b[t + 64];
}

// ---------------- tiled fp32 GEMM: C = act(A@W + bias) (+ R) --------------------
template<int ACT, bool RES>
__global__ __launch_bounds__(256) void gemm_kernel(
    const float* __restrict__ A, const float* __restrict__ W,
    const float* __restrict__ bias, const float* __restrict__ R,
    float* __restrict__ C, int M, int N, int K) {
    __shared__ float As[16][65];
    __shared__ float Bs[16][64];
    const int tid = threadIdx.x;
    const int tx = tid & 15, ty = tid >> 4;
    const int m0 = blockIdx.y * 64, n0 = blockIdx.x * 64;
    const int am = tid >> 2;
    const int ak = (tid & 3) << 2;
    const int bk = tid >> 4;
    const int bn = (tid & 15) << 2;
    float acc[4][4] = {{0.f}};
    for (int k0 = 0; k0 < K; k0 += 16) {
        float4 av = make_float4(0.f, 0.f, 0.f, 0.f);
        if (m0 + am < M) av = *(const float4*)&A[(size_t)(m0 + am) * K + k0 + ak];
        As[ak + 0][am] = av.x; As[ak + 1][am] = av.y;
        As[ak + 2][am] = av.z; As[ak + 3][am] = av.w;
        *(float4*)&Bs[bk][bn] = *(const float4*)&W[(size_t)(k0 + bk) * N + n0 + bn];
        __syncthreads();
        #pragma unroll
        for (int k = 0; k < 16; ++k) {
            float a0 = As[k][ty * 4 + 0], a1 = As[k][ty * 4 + 1];
            float a2 = As[k][ty * 4 + 2], a3 = As[k][ty * 4 + 3];
            float4 bv = *(const float4*)&Bs[k][tx * 4];
            acc[0][0] += a0 * bv.x; acc[0][1] += a0 * bv.y; acc[0][2] += a0 * bv.z; acc[0][3] += a0 * bv.w;
            acc[1][0] += a1 * bv.x; acc[1][1] += a1 * bv.y; acc[1][2] += a1 * bv.z; acc[1][3] += a1 * bv.w;
            acc[2][0] += a2 * bv.x; acc[2][1] += a2 * bv.y; acc[2][2] += a2 * bv.z; acc[2][3] += a2 * bv.w;
            acc[3][0] += a3 * bv.x; acc[3][1] += a3 * bv.y; acc[3][2] += a3 * bv.z; acc[3][3] += a3 * bv.w;
        }
        __syncthreads();
    }
    const int nn0 = n0 + tx * 4;
    float4 bias4 = *(const float4*)&bias[nn0];
    #pragma unroll
    for (int i = 0; i < 4; ++i) {
        int mm = m0 + ty * 4 + i;
        if (mm >= M) continue;
        float4 res;
        res.x = acc[i][0] + bias4.x; res.y = acc[i][1] + bias4.y;
        res.z = acc[i][2] + bias4.z; res.w = acc[i][3] + bias4.w;
        if (ACT == 1) {
            res.x = gelu_exact(res.x); res.y = gelu_exact(res.y);
            res.z = gelu_exact(res.z); res.w = gelu_exact(res.w);
        }
        if (RES) {
            float4 r4 = *(const float4*)&R[(size_t)mm * N + nn0];
            res.x += r4.x; res.y += r4.y; res.z += r4.z; res.w += r4.w;
        }
        *(float4*)&C[(size_t)mm * N + nn0] = res;
    }
}

// ---------------- attention: flash-style, fp32, dh=16, 8 heads ------------------
__global__ __launch_bounds__(256) void attn_kernel(
    const float* __restrict__ qkv, float* __restrict__ O) {
    __shared__ float Ks[256 * 16];
    __shared__ float Vs[256 * 16];
    const int t = threadIdx.x;
    const int rl = t & 63;
    const int chunk = t >> 6;
    const int head = blockIdx.y;
    const int qrow = blockIdx.x * 64 + rl;
    float q[16];
    #pragma unroll
    for (int d = 0; d < 16; ++d)
        q[d] = (qrow < SEQ) ? qkv[(size_t)qrow * 384 + head * 16 + d] : 0.f;
    float m = -INFINITY, l = 0.f;
    float acc[16];
    #pragma unroll
    for (int d = 0; d < 16; ++d) acc[d] = 0.f;

    for (int tile0 = 0; tile0 < SEQ; tile0 += 256) {
        int j = tile0 + t;
        if (j < SEQ) {
            const float* kp = &qkv[(size_t)j * 384 + 128 + head * 16];
            const float* vp = &qkv[(size_t)j * 384 + 256 + head * 16];
            #pragma unroll
            for (int d = 0; d < 16; ++d) { Ks[t * 16 + d] = kp[d]; Vs[t * 16 + d] = vp[d]; }
        }
        __syncthreads();
        int nkeys = SEQ - tile0; if (nkeys > 256) nkeys = 256;
        int base = chunk * 64;
        int cnt = nkeys - base; if (cnt > 64) cnt = 64;
        for (int jj = 0; jj < cnt; ++jj) {
            const float* kr = &Ks[(base + jj) * 16];
            float s = 0.f;
            #pragma unroll
            for (int d = 0; d < 16; ++d) s += q[d] * kr[d];
            s *= 0.25f;
            float nm = fmaxf(m, s);
            float corr = expf(m - nm);
            float e = expf(s - nm);
            l = l * corr + e;
            const float* vr = &Vs[(base + jj) * 16];
            #pragma unroll
            for (int d = 0; d < 16; ++d) acc[d] = acc[d] * corr + e * vr[d];
            m = nm;
        }
        __syncthreads();
    }
    float* pacc = Ks;
    float* pm = Vs;
    float* pl = Vs + 256;
    #pragma unroll
    for (int d = 0; d < 16; ++d) pacc[t * 16 + d] = acc[d];
    pm[t] = m; pl[t] = l;
    __syncthreads();
    if (t < 64) {
        int row = blockIdx.x * 64 + t;
        if (row < SEQ) {
            float M = -INFINITY;
            #pragma unroll
            for (int c = 0; c < 4; ++c) M = fmaxf(M, pm[c * 64 + t]);
            float L = 0.f;
            float o[16];
            #pragma unroll
            for (int d = 0; d < 16; ++d) o[d] = 0.f;
            #pragma unroll
            for (int c = 0; c < 4; ++c) {
                float w = expf(pm[c * 64 + t] - M);
                L += pl[c * 64 + t] * w;
                const float* pa = &pacc[(c * 64 + t) * 16];
                #pragma unroll
                for (int d = 0; d < 16; ++d) o[d] += pa[d] * w;
            }
            float inv = 1.f / L;
            #pragma unroll
            for (int d = 0; d < 16; ++d)
                O[(size_t)row * 128 + head * 16 + d] = o[d] * inv;
        }
    }
}

// ---- region + map_fuse + channel-LN stats (fused):
// fused = feat * rfac[p];  rfac = mean_m sigmoid(feat.key0/128) + 1
// FUSED stats over channels: mean = rfac*mean_raw, var = rfac^2*var_raw
__global__ __launch_bounds__(256) void region_fuse_stats_kernel(
    const float* __restrict__ sup, const float* __restrict__ qry,
    const float* __restrict__ X, float* __restrict__ fused,
    float* __restrict__ MEAN, float* __restrict__ RSTD) {
    __shared__ float key0[2048];   // 16 x 128
    __shared__ float rfac[100];
    const int b = blockIdx.x;
    const int t = threadIdx.x;
    const float* feat = (b < 25) ? (sup + (size_t)b * 12800) : (qry + (size_t)(b - 25) * 12800);
    for (int i = t; i < 2048; i += 256) key0[i] = X[i];
    __syncthreads();
    if (t < 100) {
        float dots[16];
        #pragma unroll
        for (int mm = 0; mm < 16; ++mm) dots[mm] = 0.f;
        float s = 0.f, ss = 0.f;
        for (int c = 0; c < 128; ++c) {
            float f = feat[c * 100 + t];
            s += f; ss += f * f;
            #pragma unroll
            for (int mm = 0; mm < 16; ++mm) dots[mm] += f * key0[mm * 128 + c];
        }
        float mean16 = 0.f;
        #pragma unroll
        for (int mm = 0; mm < 16; ++mm) mean16 += 1.f / (1.f + expf(-dots[mm] * (1.f / 128.f)));
        float r = mean16 * (1.f / 16.f) + 1.f;
        rfac[t] = r;
        float mr = s * (1.f / 128.f);
        float vr = ss * (1.f / 128.f) - mr * mr;
        MEAN[b * 128 + t] = mr * r;
        RSTD[b * 128 + t] = rsqrtf(vr * r * r + 1e-6f);
    }
    __syncthreads();
    for (int i = t; i < 12800; i += 256)
        fused[(size_t)b * 12800 + i] = feat[i] * rfac[i % 100];
}

// ---------------- 3x3 conv, pad 1, 10x10 images --------------------------------
// grid (100 images, 4 to-groups of 8), block 256. Thread: p = t&127 (p<100),
// wave-uniform half h = t>>7 selects 4 of the group's 8 output channels.
// Input staged zero-padded 12x12 in LDS (32-channel chunks); weights read from
// global with wave-uniform indices -> scalar loads. Optional fused channel-LN.
template<int CIN, bool RELU, bool FUSE_LN>
__global__ __launch_bounds__(256) void conv3x3_kernel(
    const float* __restrict__ in, const float* __restrict__ w,
    const float* __restrict__ MEAN, const float* __restrict__ RSTD,
    const float* __restrict__ g, const float* __restrict__ bb,
    float* __restrict__ out) {
    __shared__ float sin_[32 * 144];
    const int b = blockIdx.x;
    const int base_to = blockIdx.y * 8;
    const int t = threadIdx.x;
    const int h = __builtin_amdgcn_readfirstlane(t >> 7);   // wave-uniform
    const int p = t & 127;
    const int py = p / 10, px = p - py * 10;
    const bool active = p < 100;
    float acc[4] = {0.f, 0.f, 0.f, 0.f};
    for (int cb = 0; cb < CIN; cb += 32) {
        if (cb) __syncthreads();
        for (int i = t; i < 32 * 144; i += 256) {
            int c = i / 144, pos = i - c * 144;
            int y = pos / 12 - 1, x = pos % 12 - 1;
            float v = 0.f;
            if ((unsigned)y < 10u && (unsigned)x < 10u) {
                int pp = y * 10 + x;
                float raw = in[(size_t)b * CIN * 100 + (cb + c) * 100 + pp];
                if (FUSE_LN)
                    v = (raw - MEAN[b * 128 + pp]) * RSTD[b * 128 + pp] * g[cb + c] + bb[cb + c];
                else
                    v = raw;
            }
            sin_[i] = v;
        }
        __syncthreads();
        if (active) {
            const float* wbase = w + ((size_t)(base_to + h * 4) * CIN + cb) * 9;
            for (int c = 0; c < 32; ++c) {
                const float* sp = &sin_[c * 144 + py * 12 + px];
                float pix[9];
                #pragma unroll
                for (int k = 0; k < 9; ++k) pix[k] = sp[(k / 3) * 12 + (k % 3)];
                #pragma unroll
                for (int j = 0; j < 4; ++j) {
                    const float* wq = wbase + ((size_t)j * CIN + c) * 9;
                    #pragma unroll
                    for (int k = 0; k < 9; ++k) acc[j] = fmaf(pix[k], wq[k], acc[j]);
                }
            }
        }
    }
    if (active) {
        #pragma unroll
        for (int j = 0; j < 4; ++j) {
            float v = acc[j];
            if (RELU) v = fmaxf(v, 0.f);
            out[(size_t)b * 3200 + (base_to + h * 4 + j) * 100 + p] = v;
        }
    }
}

// ---------------- final pooling: out[b,c,t] = (1/100) sum_p sigmoid(conv4)*fused -
__global__ __launch_bounds__(256) void rfm_out_kernel(
    const float* __restrict__ conv4, const float* __restrict__ fused, float* __restrict__ out) {
    __shared__ float sig[3200];
    __shared__ float sf[12800];
    const int b = blockIdx.x;
    const int t = threadIdx.x;
    for (int i = t; i < 3200; i += 256) sig[i] = 1.f / (1.f + expf(-conv4[(size_t)b * 3200 + i]));
    for (int i = t; i < 12800; i += 256) sf[i] = fused[(size_t)b * 12800 + i];
    __syncthreads();
    for (int o = t; o < 4096; o += 256) {
        int c = o >> 5, tt = o & 31;
        float acc = 0.f;
        for (int p = 0; p < 100; ++p) acc += sig[tt * 100 + p] * sf[c * 100 + p];
        out[(size_t)b * 4096 + o] = acc * 0.01f;
    }
}

extern "C" void kernel_launch(void* const* d_in, const int* in_sizes, int n_in,
                              void* d_out, int out_size, void* d_ws, size_t ws_size,
                              hipStream_t stream) {
    (void)in_sizes; (void)n_in; (void)out_size; (void)ws_size;
    const float* sup    = (const float*)d_in[0];
    const float* qry    = (const float*)d_in[1];
    const float* td     = (const float*)d_in[2];
    const float* ln1_g  = (const float*)d_in[3];
    const float* ln1_b  = (const float*)d_in[4];
    const float* qkv_w  = (const float*)d_in[5];
    const float* qkv_b  = (const float*)d_in[6];
    const float* out_w  = (const float*)d_in[7];
    const float* out_b  = (const float*)d_in[8];
    const float* ln2_g  = (const float*)d_in[9];
    const float* ln2_b  = (const float*)d_in[10];
    const float* mlp_w1 = (const float*)d_in[11];
    const float* mlp_b1 = (const float*)d_in[12];
    const float* mlp_w2 = (const float*)d_in[13];
    const float* mlp_b2 = (const float*)d_in[14];
    const float* rg     = (const float*)d_in[15];
    const float* rb     = (const float*)d_in[16];
    const float* c1     = (const float*)d_in[17];
    const float* c2     = (const float*)d_in[18];
    const float* c3     = (const float*)d_in[19];
    const float* c4     = (const float*)d_in[20];
    float* out = (float*)d_out;

    float* ws   = (float*)d_ws;
    float* X    = ws;                  // 322048
    float* H    = X + 322048;          // 322048
    float* QKV  = H + 322048;          // 966144
    float* Obuf = QKV + 966144;        // 322048
    float* MLPH = Obuf + 322048;       // 1288192
    float* FUSED= MLPH + 1288192;      // 1280000
    float* MEAN = FUSED + 1280000;     // 12800
    float* RSTD = MEAN + 12800;        // 12800
    float* CB1  = RSTD + 12800;        // 320000
    float* CB2  = CB1 + 320000;        // 320000

    concat_kernel<<<(SEQ * CDIM + 255) / 256, 256, 0, stream>>>(td, sup, X);
    for (int i = 0; i < 2; ++i) {
        ln_row_kernel<<<SEQ, 64, 0, stream>>>(X, H, ln1_g + i * 128, ln1_b + i * 128, 1e-5f);
        gemm_kernel<0, false><<<dim3(6, 40), 256, 0, stream>>>(
            H, qkv_w + (size_t)i * 128 * 384, qkv_b + i * 384, nullptr, QKV, SEQ, 384, 128);
        attn_kernel<<<dim3(40, 8), 256, 0, stream>>>(QKV, Obuf);
        gemm_kernel<0, true><<<dim3(2, 40), 256, 0, stream>>>(
            Obuf, out_w + (size_t)i * 128 * 128, out_b + i * 128, X, X, SEQ, 128, 128);
        ln_row_kernel<<<SEQ, 64, 0, stream>>>(X, H, ln2_g + i * 128, ln2_b + i * 128, 1e-5f);
        gemm_kernel<1, false><<<dim3(8, 40), 256, 0, stream>>>(
            H, mlp_w1 + (size_t)i * 128 * 512, mlp_b1 + i * 512, nullptr, MLPH, SEQ, 512, 128);
        gemm_kernel<0, true><<<dim3(2, 40), 256, 0, stream>>>(
            MLPH, mlp_w2 + (size_t)i * 512 * 128, mlp_b2 + i * 128, X, X, SEQ, 128, 512);
    }
    region_fuse_stats_kernel<<<100, 256, 0, stream>>>(sup, qry, X, FUSED, MEAN, RSTD);
    conv3x3_kernel<128, true,  true ><<<dim3(100, 4), 256, 0, stream>>>(FUSED, c1, MEAN, RSTD, rg, rb, CB1);
    conv3x3_kernel< 32, true,  false><<<dim3(100, 4), 256, 0, stream>>>(CB1, c2, nullptr, nullptr, nullptr, nullptr, CB2);
    conv3x3_kernel< 32, true,  false><<<dim3(100, 4), 256, 0, stream>>>(CB2, c3, nullptr, nullptr, nullptr, nullptr, CB1);
    conv3x3_kernel< 32, false, false><<<dim3(100, 4), 256, 0, stream>>>(CB1, c4, nullptr, nullptr, nullptr, nullptr, CB2);
    rfm_out_kernel<<<100, 256, 0, stream>>>(CB2, FUSED, out);
}

// Round 3
// 661.667 us; speedup vs baseline: 1.6763x; 1.2277x over previous
//
#include <hip/hip_runtime.h>
#include <math.h>

#define SEQ 2516
#define CDIM 128

__device__ __forceinline__ float gelu_exact(float x) {
    return x * 0.5f * (1.0f + erff(x * 0.7071067811865475f));
}

// ---------------- build x = concat(task_descriptor, support.transpose(0,2,3,1)) ----
__global__ __launch_bounds__(256) void concat_kernel(
    const float* __restrict__ td, const float* __restrict__ sup, float* __restrict__ X) {
    int i = blockIdx.x * 256 + threadIdx.x;
    if (i >= SEQ * CDIM) return;
    int row = i >> 7, c = i & 127;
    if (row < 16) {
        X[i] = td[i];
    } else {
        int r = row - 16;
        int n = r / 100, p = r - n * 100;
        X[i] = sup[n * 12800 + c * 100 + p];
    }
}

// ---------------- row layernorm over last dim (128), 1 wave per row -------------
__global__ __launch_bounds__(64) void ln_row_kernel(
    const float* __restrict__ in, float* __restrict__ out,
    const float* __restrict__ g, const float* __restrict__ b, float eps) {
    const int row = blockIdx.x;
    const int t = threadIdx.x;
    float x0 = in[row * 128 + t];
    float x1 = in[row * 128 + 64 + t];
    float s = x0 + x1;
    for (int off = 32; off > 0; off >>= 1) s += __shfl_down(s, off);
    float mean = __shfl(s, 0) * (1.f / 128.f);
    float d0 = x0 - mean, d1 = x1 - mean;
    float v = d0 * d0 + d1 * d1;
    for (int off = 32; off > 0; off >>= 1) v += __shfl_down(v, off);
    float var = __shfl(v, 0) * (1.f / 128.f);
    float rstd = rsqrtf(var + eps);
    out[row * 128 + t]      = d0 * rstd * g[t] + b[t];
    out[row * 128 + 64 + t] = d1 * rstd * g[t + 64] + b[t + 64];
}

// ---------------- tiled fp32 GEMM: C = act(A@W + bias) (+ R) --------------------
template<int ACT, bool RES>
__global__ __launch_bounds__(256) void gemm_kernel(
    const float* __restrict__ A, const float* __restrict__ W,
    const float* __restrict__ bias, const float* __restrict__ R,
    float* __restrict__ C, int M, int N, int K) {
    __shared__ float As[16][65];
    __shared__ float Bs[16][64];
    const int tid = threadIdx.x;
    const int tx = tid & 15, ty = tid >> 4;
    const int m0 = blockIdx.y * 64, n0 = blockIdx.x * 64;
    const int am = tid >> 2;
    const int ak = (tid & 3) << 2;
    const int bk = tid >> 4;
    const int bn = (tid & 15) << 2;
    float acc[4][4] = {{0.f}};
    for (int k0 = 0; k0 < K; k0 += 16) {
        float4 av = make_float4(0.f, 0.f, 0.f, 0.f);
        if (m0 + am < M) av = *(const float4*)&A[(size_t)(m0 + am) * K + k0 + ak];
        As[ak + 0][am] = av.x; As[ak + 1][am] = av.y;
        As[ak + 2][am] = av.z; As[ak + 3][am] = av.w;
        *(float4*)&Bs[bk][bn] = *(const float4*)&W[(size_t)(k0 + bk) * N + n0 + bn];
        __syncthreads();
        #pragma unroll
        for (int k = 0; k < 16; ++k) {
            float a0 = As[k][ty * 4 + 0], a1 = As[k][ty * 4 + 1];
            float a2 = As[k][ty * 4 + 2], a3 = As[k][ty * 4 + 3];
            float4 bv = *(const float4*)&Bs[k][tx * 4];
            acc[0][0] += a0 * bv.x; acc[0][1] += a0 * bv.y; acc[0][2] += a0 * bv.z; acc[0][3] += a0 * bv.w;
            acc[1][0] += a1 * bv.x; acc[1][1] += a1 * bv.y; acc[1][2] += a1 * bv.z; acc[1][3] += a1 * bv.w;
            acc[2][0] += a2 * bv.x; acc[2][1] += a2 * bv.y; acc[2][2] += a2 * bv.z; acc[2][3] += a2 * bv.w;
            acc[3][0] += a3 * bv.x; acc[3][1] += a3 * bv.y; acc[3][2] += a3 * bv.z; acc[3][3] += a3 * bv.w;
        }
        __syncthreads();
    }
    const int nn0 = n0 + tx * 4;
    float4 bias4 = *(const float4*)&bias[nn0];
    #pragma unroll
    for (int i = 0; i < 4; ++i) {
        int mm = m0 + ty * 4 + i;
        if (mm >= M) continue;
        float4 res;
        res.x = acc[i][0] + bias4.x; res.y = acc[i][1] + bias4.y;
        res.z = acc[i][2] + bias4.z; res.w = acc[i][3] + bias4.w;
        if (ACT == 1) {
            res.x = gelu_exact(res.x); res.y = gelu_exact(res.y);
            res.z = gelu_exact(res.z); res.w = gelu_exact(res.w);
        }
        if (RES) {
            float4 r4 = *(const float4*)&R[(size_t)mm * N + nn0];
            res.x += r4.x; res.y += r4.y; res.z += r4.z; res.w += r4.w;
        }
        *(float4*)&C[(size_t)mm * N + nn0] = res;
    }
}

// ---------------- attention v3: fp32, log2-domain, group-of-4 online softmax ----
// Block 512 thr (8 waves): lane rl = t&63 is a query row, chunk = t>>6 (8-way
// key split). K/V tiles of 256 keys in LDS, rows padded to 20 floats (80 B,
// float4-aligned, stride covers all 32 banks per 8 lanes on staging writes).
// Scores carry scale*log2e folded into Q; exp2f is native v_exp_f32.
__device__ __forceinline__ float dot16(
    const float4 q0, const float4 q1, const float4 q2, const float4 q3,
    const float4* __restrict__ k) {
    float4 ka = k[0], kb = k[1], kc = k[2], kd = k[3];
    float s = q0.x * ka.x + q0.y * ka.y + q0.z * ka.z + q0.w * ka.w;
    s += q1.x * kb.x + q1.y * kb.y + q1.z * kb.z + q1.w * kb.w;
    s += q2.x * kc.x + q2.y * kc.y + q2.z * kc.z + q2.w * kc.w;
    s += q3.x * kd.x + q3.y * kd.y + q3.z * kd.z + q3.w * kd.w;
    return s;
}

__device__ __forceinline__ float4 upd4(
    float4 a, float corr,
    float e0, const float4 v0, float e1, const float4 v1,
    float e2, const float4 v2, float e3, const float4 v3) {
    float4 r;
    r.x = fmaf(a.x, corr, fmaf(e0, v0.x, fmaf(e1, v1.x, fmaf(e2, v2.x, e3 * v3.x))));
    r.y = fmaf(a.y, corr, fmaf(e0, v0.y, fmaf(e1, v1.y, fmaf(e2, v2.y, e3 * v3.y))));
    r.z = fmaf(a.z, corr, fmaf(e0, v0.z, fmaf(e1, v1.z, fmaf(e2, v2.z, e3 * v3.z))));
    r.w = fmaf(a.w, corr, fmaf(e0, v0.w, fmaf(e1, v1.w, fmaf(e2, v2.w, e3 * v3.w))));
    return r;
}

__global__ __launch_bounds__(512) void attn_kernel(
    const float* __restrict__ qkv, float* __restrict__ O) {
    __shared__ float lds[10240];           // 40 KB
    float* Ks = lds;                       // 256*20
    float* Vs = lds + 5120;                // 256*20
    const int t = threadIdx.x;
    const int rl = t & 63;
    const int chunk = t >> 6;              // 0..7
    const int head = blockIdx.y;
    const int qrow = blockIdx.x * 64 + rl;
    const float SC = 0.25f * 1.4426950408889634f;   // log2e / sqrt(dh)
    float4 q0 = make_float4(0.f, 0.f, 0.f, 0.f), q1 = q0, q2 = q0, q3 = q0;
    if (qrow < SEQ) {
        const float4* qp = (const float4*)&qkv[(size_t)qrow * 384 + head * 16];
        q0 = qp[0]; q1 = qp[1]; q2 = qp[2]; q3 = qp[3];
        q0.x *= SC; q0.y *= SC; q0.z *= SC; q0.w *= SC;
        q1.x *= SC; q1.y *= SC; q1.z *= SC; q1.w *= SC;
        q2.x *= SC; q2.y *= SC; q2.z *= SC; q2.w *= SC;
        q3.x *= SC; q3.y *= SC; q3.z *= SC; q3.w *= SC;
    }
    float m = -INFINITY, l = 0.f;
    float4 a0 = make_float4(0.f, 0.f, 0.f, 0.f), a1 = a0, a2 = a0, a3 = a0;
    const int kk = t >> 1, half = t & 1;

    for (int tile0 = 0; tile0 < SEQ; tile0 += 256) {
        if (tile0) __syncthreads();
        int j = tile0 + kk;
        if (j < SEQ) {
            const float4* kp = (const float4*)&qkv[(size_t)j * 384 + 128 + head * 16 + half * 8];
            const float4* vp = (const float4*)&qkv[(size_t)j * 384 + 256 + head * 16 + half * 8];
            float4* kd = (float4*)&Ks[kk * 20 + half * 8];
            float4* vd = (float4*)&Vs[kk * 20 + half * 8];
            kd[0] = kp[0]; kd[1] = kp[1];
            vd[0] = vp[0]; vd[1] = vp[1];
        }
        __syncthreads();
        int cnt = SEQ - tile0; if (cnt > 256) cnt = 256;
        int cc = cnt - chunk * 32; if (cc < 0) cc = 0; if (cc > 32) cc = 32;
        const int base = chunk * 32;
        for (int jj = 0; jj < cc; jj += 4) {
            const int j0 = base + jj;
            float s0 = dot16(q0, q1, q2, q3, (const float4*)&Ks[(j0 + 0) * 20]);
            float s1 = dot16(q0, q1, q2, q3, (const float4*)&Ks[(j0 + 1) * 20]);
            float s2 = dot16(q0, q1, q2, q3, (const float4*)&Ks[(j0 + 2) * 20]);
            float s3 = dot16(q0, q1, q2, q3, (const float4*)&Ks[(j0 + 3) * 20]);
            float gm = fmaxf(fmaxf(s0, s1), fmaxf(s2, s3));
            float nm = fmaxf(m, gm);
            float corr = exp2f(m - nm);
            float e0 = exp2f(s0 - nm), e1 = exp2f(s1 - nm);
            float e2 = exp2f(s2 - nm), e3 = exp2f(s3 - nm);
            l = fmaf(l, corr, (e0 + e1) + (e2 + e3));
            const float4* v0p = (const float4*)&Vs[(j0 + 0) * 20];
            const float4* v1p = (const float4*)&Vs[(j0 + 1) * 20];
            const float4* v2p = (const float4*)&Vs[(j0 + 2) * 20];
            const float4* v3p = (const float4*)&Vs[(j0 + 3) * 20];
            a0 = upd4(a0, corr, e0, v0p[0], e1, v1p[0], e2, v2p[0], e3, v3p[0]);
            a1 = upd4(a1, corr, e0, v0p[1], e1, v1p[1], e2, v2p[1], e3, v3p[1]);
            a2 = upd4(a2, corr, e0, v0p[2], e1, v1p[2], e2, v2p[2], e3, v3p[2]);
            a3 = upd4(a3, corr, e0, v0p[3], e1, v1p[3], e2, v2p[3], e3, v3p[3]);
            m = nm;
        }
    }
    __syncthreads();
    // combine 8 chunks per query row via LDS
    float* pacc = lds;            // 512*16 = 8192
    float* pm   = lds + 8192;     // 512
    float* pl   = lds + 8704;     // 512
    float4* pa = (float4*)&pacc[t * 16];
    pa[0] = a0; pa[1] = a1; pa[2] = a2; pa[3] = a3;
    pm[t] = m; pl[t] = l;
    __syncthreads();
    if (t < 64) {
        int row = blockIdx.x * 64 + t;
        if (row < SEQ) {
            float M = -INFINITY;
            #pragma unroll
            for (int c = 0; c < 8; ++c) M = fmaxf(M, pm[c * 64 + t]);
            float L = 0.f;
            float4 o0 = make_float4(0.f, 0.f, 0.f, 0.f), o1 = o0, o2 = o0, o3 = o0;
            #pragma unroll
            for (int c = 0; c < 8; ++c) {
                float wgt = exp2f(pm[c * 64 + t] - M);
                L = fmaf(pl[c * 64 + t], wgt, L);
                const float4* pac = (const float4*)&pacc[(c * 64 + t) * 16];
                float4 b0 = pac[0], b1 = pac[1], b2 = pac[2], b3 = pac[3];
                o0.x = fmaf(b0.x, wgt, o0.x); o0.y = fmaf(b0.y, wgt, o0.y);
                o0.z = fmaf(b0.z, wgt, o0.z); o0.w = fmaf(b0.w, wgt, o0.w);
                o1.x = fmaf(b1.x, wgt, o1.x); o1.y = fmaf(b1.y, wgt, o1.y);
                o1.z = fmaf(b1.z, wgt, o1.z); o1.w = fmaf(b1.w, wgt, o1.w);
                o2.x = fmaf(b2.x, wgt, o2.x); o2.y = fmaf(b2.y, wgt, o2.y);
                o2.z = fmaf(b2.z, wgt, o2.z); o2.w = fmaf(b2.w, wgt, o2.w);
                o3.x = fmaf(b3.x, wgt, o3.x); o3.y = fmaf(b3.y, wgt, o3.y);
                o3.z = fmaf(b3.z, wgt, o3.z); o3.w = fmaf(b3.w, wgt, o3.w);
            }
            float inv = 1.f / L;
            float4* op = (float4*)&O[(size_t)row * 128 + head * 16];
            o0.x *= inv; o0.y *= inv; o0.z *= inv; o0.w *= inv;
            o1.x *= inv; o1.y *= inv; o1.z *= inv; o1.w *= inv;
            o2.x *= inv; o2.y *= inv; o2.z *= inv; o2.w *= inv;
            o3.x *= inv; o3.y *= inv; o3.z *= inv; o3.w *= inv;
            op[0] = o0; op[1] = o1; op[2] = o2; op[3] = o3;
        }
    }
}

// ---- region + map_fuse + channel-LN stats (fused) ------------------------------
__global__ __launch_bounds__(256) void region_fuse_stats_kernel(
    const float* __restrict__ sup, const float* __restrict__ qry,
    const float* __restrict__ X, float* __restrict__ fused,
    float* __restrict__ MEAN, float* __restrict__ RSTD) {
    __shared__ float key0[2048];   // 16 x 128
    __shared__ float rfac[100];
    const int b = blockIdx.x;
    const int t = threadIdx.x;
    const float* feat = (b < 25) ? (sup + (size_t)b * 12800) : (qry + (size_t)(b - 25) * 12800);
    for (int i = t; i < 2048; i += 256) key0[i] = X[i];
    __syncthreads();
    if (t < 100) {
        float dots[16];
        #pragma unroll
        for (int mm = 0; mm < 16; ++mm) dots[mm] = 0.f;
        float s = 0.f, ss = 0.f;
        for (int c = 0; c < 128; ++c) {
            float f = feat[c * 100 + t];
            s += f; ss += f * f;
            #pragma unroll
            for (int mm = 0; mm < 16; ++mm) dots[mm] += f * key0[mm * 128 + c];
        }
        float mean16 = 0.f;
        #pragma unroll
        for (int mm = 0; mm < 16; ++mm) mean16 += 1.f / (1.f + expf(-dots[mm] * (1.f / 128.f)));
        float r = mean16 * (1.f / 16.f) + 1.f;
        rfac[t] = r;
        float mr = s * (1.f / 128.f);
        float vr = ss * (1.f / 128.f) - mr * mr;
        MEAN[b * 128 + t] = mr * r;
        RSTD[b * 128 + t] = rsqrtf(vr * r * r + 1e-6f);
    }
    __syncthreads();
    for (int i = t; i < 12800; i += 256)
        fused[(size_t)b * 12800 + i] = feat[i] * rfac[i % 100];
}

// ---------------- 3x3 conv, pad 1, 10x10 images --------------------------------
template<int CIN, bool RELU, bool FUSE_LN>
__global__ __launch_bounds__(256) void conv3x3_kernel(
    const float* __restrict__ in, const float* __restrict__ w,
    const float* __restrict__ MEAN, const float* __restrict__ RSTD,
    const float* __restrict__ g, const float* __restrict__ bb,
    float* __restrict__ out) {
    __shared__ float sin_[32 * 144];
    const int b = blockIdx.x;
    const int base_to = blockIdx.y * 8;
    const int t = threadIdx.x;
    const int h = __builtin_amdgcn_readfirstlane(t >> 7);   // wave-uniform
    const int p = t & 127;
    const int py = p / 10, px = p - py * 10;
    const bool active = p < 100;
    float acc[4] = {0.f, 0.f, 0.f, 0.f};
    for (int cb = 0; cb < CIN; cb += 32) {
        if (cb) __syncthreads();
        for (int i = t; i < 32 * 144; i += 256) {
            int c = i / 144, pos = i - c * 144;
            int y = pos / 12 - 1, x = pos % 12 - 1;
            float v = 0.f;
            if ((unsigned)y < 10u && (unsigned)x < 10u) {
                int pp = y * 10 + x;
                float raw = in[(size_t)b * CIN * 100 + (cb + c) * 100 + pp];
                if (FUSE_LN)
                    v = (raw - MEAN[b * 128 + pp]) * RSTD[b * 128 + pp] * g[cb + c] + bb[cb + c];
                else
                    v = raw;
            }
            sin_[i] = v;
        }
        __syncthreads();
        if (active) {
            const float* wbase = w + ((size_t)(base_to + h * 4) * CIN + cb) * 9;
            for (int c = 0; c < 32; ++c) {
                const float* sp = &sin_[c * 144 + py * 12 + px];
                float pix[9];
                #pragma unroll
                for (int k = 0; k < 9; ++k) pix[k] = sp[(k / 3) * 12 + (k % 3)];
                #pragma unroll
                for (int j = 0; j < 4; ++j) {
                    const float* wq = wbase + ((size_t)j * CIN + c) * 9;
                    #pragma unroll
                    for (int k = 0; k < 9; ++k) acc[j] = fmaf(pix[k], wq[k], acc[j]);
                }
            }
        }
    }
    if (active) {
        #pragma unroll
        for (int j = 0; j < 4; ++j) {
            float v = acc[j];
            if (RELU) v = fmaxf(v, 0.f);
            out[(size_t)b * 3200 + (base_to + h * 4 + j) * 100 + p] = v;
        }
    }
}

// ---------------- final pooling -------------------------------------------------
__global__ __launch_bounds__(256) void rfm_out_kernel(
    const float* __restrict__ conv4, const float* __restrict__ fused, float* __restrict__ out) {
    __shared__ float sig[3200];
    __shared__ float sf[12800];
    const int b = blockIdx.x;
    const int t = threadIdx.x;
    for (int i = t; i < 3200; i += 256) sig[i] = 1.f / (1.f + expf(-conv4[(size_t)b * 3200 + i]));
    for (int i = t; i < 12800; i += 256) sf[i] = fused[(size_t)b * 12800 + i];
    __syncthreads();
    for (int o = t; o < 4096; o += 256) {
        int c = o >> 5, tt = o & 31;
        float acc = 0.f;
        for (int p = 0; p < 100; ++p) acc += sig[tt * 100 + p] * sf[c * 100 + p];
        out[(size_t)b * 4096 + o] = acc * 0.01f;
    }
}

extern "C" void kernel_launch(void* const* d_in, const int* in_sizes, int n_in,
                              void* d_out, int out_size, void* d_ws, size_t ws_size,
                              hipStream_t stream) {
    (void)in_sizes; (void)n_in; (void)out_size; (void)ws_size;
    const float* sup    = (const float*)d_in[0];
    const float* qry    = (const float*)d_in[1];
    const float* td     = (const float*)d_in[2];
    const float* ln1_g  = (const float*)d_in[3];
    const float* ln1_b  = (const float*)d_in[4];
    const float* qkv_w  = (const float*)d_in[5];
    const float* qkv_b  = (const float*)d_in[6];
    const float* out_w  = (const float*)d_in[7];
    const float* out_b  = (const float*)d_in[8];
    const float* ln2_g  = (const float*)d_in[9];
    const float* ln2_b  = (const float*)d_in[10];
    const float* mlp_w1 = (const float*)d_in[11];
    const float* mlp_b1 = (const float*)d_in[12];
    const float* mlp_w2 = (const float*)d_in[13];
    const float* mlp_b2 = (const float*)d_in[14];
    const float* rg     = (const float*)d_in[15];
    const float* rb     = (const float*)d_in[16];
    const float* c1     = (const float*)d_in[17];
    const float* c2     = (const float*)d_in[18];
    const float* c3     = (const float*)d_in[19];
    const float* c4     = (const float*)d_in[20];
    float* out = (float*)d_out;

    float* ws   = (float*)d_ws;
    float* X    = ws;                  // 322048
    float* H    = X + 322048;          // 322048
    float* QKV  = H + 322048;          // 966144
    float* Obuf = QKV + 966144;        // 322048
    float* MLPH = Obuf + 322048;       // 1288192
    float* FUSED= MLPH + 1288192;      // 1280000
    float* MEAN = FUSED + 1280000;     // 12800
    float* RSTD = MEAN + 12800;        // 12800
    float* CB1  = RSTD + 12800;        // 320000
    float* CB2  = CB1 + 320000;        // 320000

    concat_kernel<<<(SEQ * CDIM + 255) / 256, 256, 0, stream>>>(td, sup, X);
    for (int i = 0; i < 2; ++i) {
        ln_row_kernel<<<SEQ, 64, 0, stream>>>(X, H, ln1_g + i * 128, ln1_b + i * 128, 1e-5f);
        gemm_kernel<0, false><<<dim3(6, 40), 256, 0, stream>>>(
            H, qkv_w + (size_t)i * 128 * 384, qkv_b + i * 384, nullptr, QKV, SEQ, 384, 128);
        attn_kernel<<<dim3(40, 8), 512, 0, stream>>>(QKV, Obuf);
        gemm_kernel<0, true><<<dim3(2, 40), 256, 0, stream>>>(
            Obuf, out_w + (size_t)i * 128 * 128, out_b + i * 128, X, X, SEQ, 128, 128);
        ln_row_kernel<<<SEQ, 64, 0, stream>>>(X, H, ln2_g + i * 128, ln2_b + i * 128, 1e-5f);
        gemm_kernel<1, false><<<dim3(8, 40), 256, 0, stream>>>(
            H, mlp_w1 + (size_t)i * 128 * 512, mlp_b1 + i * 512, nullptr, MLPH, SEQ, 512, 128);
        gemm_kernel<0, true><<<dim3(2, 40), 256, 0, stream>>>(
            MLPH, mlp_w2 + (size_t)i * 512 * 128, mlp_b2 + i * 128, X, X, SEQ, 128, 512);
    }
    region_fuse_stats_kernel<<<100, 256, 0, stream>>>(sup, qry, X, FUSED, MEAN, RSTD);
    conv3x3_kernel<128, true,  true ><<<dim3(100, 4), 256, 0, stream>>>(FUSED, c1, MEAN, RSTD, rg, rb, CB1);
    conv3x3_kernel< 32, true,  false><<<dim3(100, 4), 256, 0, stream>>>(CB1, c2, nullptr, nullptr, nullptr, nullptr, CB2);
    conv3x3_kernel< 32, true,  false><<<dim3(100, 4), 256, 0, stream>>>(CB2, c3, nullptr, nullptr, nullptr, nullptr, CB1);
    conv3x3_kernel< 32, false, false><<<dim3(100, 4), 256, 0, stream>>>(CB1, c4, nullptr, nullptr, nullptr, nullptr, CB2);
    rfm_out_kernel<<<100, 256, 0, stream>>>(CB2, FUSED, out);
}

// Round 4
// 633.711 us; speedup vs baseline: 1.7502x; 1.0441x over previous
//
#include <hip/hip_runtime.h>
#include <math.h>

#define SEQ 2516
#define CDIM 128

__device__ __forceinline__ float gelu_exact(float x) {
    return x * 0.5f * (1.0f + erff(x * 0.7071067811865475f));
}

// ---------------- build x = concat(task_descriptor, support.transpose(0,2,3,1)) ----
__global__ __launch_bounds__(256) void concat_kernel(
    const float* __restrict__ td, const float* __restrict__ sup, float* __restrict__ X) {
    int i = blockIdx.x * 256 + threadIdx.x;
    if (i >= SEQ * CDIM) return;
    int row = i >> 7, c = i & 127;
    if (row < 16) {
        X[i] = td[i];
    } else {
        int r = row - 16;
        int n = r / 100, p = r - n * 100;
        X[i] = sup[n * 12800 + c * 100 + p];
    }
}

// ---------------- row layernorm over last dim (128), 1 wave per row -------------
__global__ __launch_bounds__(64) void ln_row_kernel(
    const float* __restrict__ in, float* __restrict__ out,
    const float* __restrict__ g, const float* __restrict__ b, float eps) {
    const int row = blockIdx.x;
    const int t = threadIdx.x;
    float x0 = in[row * 128 + t];
    float x1 = in[row * 128 + 64 + t];
    float s = x0 + x1;
    for (int off = 32; off > 0; off >>= 1) s += __shfl_down(s, off);
    float mean = __shfl(s, 0) * (1.f / 128.f);
    float d0 = x0 - mean, d1 = x1 - mean;
    float v = d0 * d0 + d1 * d1;
    for (int off = 32; off > 0; off >>= 1) v += __shfl_down(v, off);
    float var = __shfl(v, 0) * (1.f / 128.f);
    float rstd = rsqrtf(var + eps);
    out[row * 128 + t]      = d0 * rstd * g[t] + b[t];
    out[row * 128 + 64 + t] = d1 * rstd * g[t + 64] + b[t + 64];
}

// ---------------- skinny GEMM: 8 M-rows x N cols per block ----------------------
// block = N*8/RPT threads; thread: col c = t%N, row-group grp = t/N (wave-uniform
// -> readfirstlane -> A reads become s_load). W reads coalesced, L2-resident.
// A padded to 2520 rows in ws; OOB-row stores guarded.
template<int N, int RPT, int ACT, bool RES>
__global__ __launch_bounds__(N * 8 / RPT) void sgemm_kernel(
    const float* __restrict__ A, const float* __restrict__ W,
    const float* __restrict__ bias, const float* __restrict__ R,
    float* __restrict__ C, int M, int K) {
    const int t = threadIdx.x;
    const int c = t % N;
    const int grp = __builtin_amdgcn_readfirstlane(t / N);
    const int r0 = blockIdx.x * 8 + grp * RPT;
    float acc[RPT];
    #pragma unroll
    for (int i = 0; i < RPT; ++i) acc[i] = 0.f;
    #pragma unroll 4
    for (int k0 = 0; k0 < K; k0 += 4) {
        float w0 = W[(size_t)(k0 + 0) * N + c];
        float w1 = W[(size_t)(k0 + 1) * N + c];
        float w2 = W[(size_t)(k0 + 2) * N + c];
        float w3 = W[(size_t)(k0 + 3) * N + c];
        #pragma unroll
        for (int i = 0; i < RPT; ++i) {
            float4 a4 = *(const float4*)&A[(size_t)(r0 + i) * K + k0];
            acc[i] = fmaf(a4.x, w0, acc[i]);
            acc[i] = fmaf(a4.y, w1, acc[i]);
            acc[i] = fmaf(a4.z, w2, acc[i]);
            acc[i] = fmaf(a4.w, w3, acc[i]);
        }
    }
    float bv = bias[c];
    #pragma unroll
    for (int i = 0; i < RPT; ++i) {
        int row = r0 + i;
        if (row < M) {
            float v = acc[i] + bv;
            if (ACT == 1) v = gelu_exact(v);
            if (RES) v += R[(size_t)row * N + c];
            C[(size_t)row * N + c] = v;
        }
    }
}

// ---------------- attention v4: fp32, QB=4 queries/thread ------------------------
// grid (40, 8 heads), block 256 (4 waves). Thread: qg = t&15 -> 4 query rows
// qbase..qbase+3; chunk = t>>4 (16 chunks x 16 keys per 256-key tile).
// Each K/V LDS row read serves 4 dots -> 4x less LDS-pipe traffic than QB=1.
// Final: shfl_xor(16,32) merges the 4 chunks within a wave, LDS merges 4 waves.
__global__ __launch_bounds__(256) void attn_kernel(
    const float* __restrict__ qkv, float* __restrict__ O) {
    __shared__ float lds[10240];           // 40 KB
    float* Ks = lds;                       // 256*20
    float* Vs = lds + 5120;                // 256*20
    const int t = threadIdx.x;
    const int qg = t & 15;
    const int chunk = t >> 4;              // 0..15
    const int head = blockIdx.y;
    const int qbase = blockIdx.x * 64 + qg * 4;
    const float SC = 0.25f * 1.4426950408889634f;   // log2e / sqrt(dh)

    float4 q[4][4];
    #pragma unroll
    for (int i = 0; i < 4; ++i) {
        if (qbase + i < SEQ) {
            const float4* qp = (const float4*)&qkv[(size_t)(qbase + i) * 384 + head * 16];
            #pragma unroll
            for (int j = 0; j < 4; ++j) {
                float4 v = qp[j];
                v.x *= SC; v.y *= SC; v.z *= SC; v.w *= SC;
                q[i][j] = v;
            }
        } else {
            #pragma unroll
            for (int j = 0; j < 4; ++j) q[i][j] = make_float4(0.f, 0.f, 0.f, 0.f);
        }
    }
    float m[4] = {-INFINITY, -INFINITY, -INFINITY, -INFINITY};
    float l[4] = {0.f, 0.f, 0.f, 0.f};
    float4 acc[4][4];
    #pragma unroll
    for (int i = 0; i < 4; ++i)
        #pragma unroll
        for (int j = 0; j < 4; ++j) acc[i][j] = make_float4(0.f, 0.f, 0.f, 0.f);

    for (int tile0 = 0; tile0 < SEQ; tile0 += 256) {
        if (tile0) __syncthreads();
        int j = tile0 + t;
        if (j < SEQ) {
            const float4* kp = (const float4*)&qkv[(size_t)j * 384 + 128 + head * 16];
            const float4* vp = (const float4*)&qkv[(size_t)j * 384 + 256 + head * 16];
            float4* kd = (float4*)&Ks[t * 20];
            float4* vd = (float4*)&Vs[t * 20];
            kd[0] = kp[0]; kd[1] = kp[1]; kd[2] = kp[2]; kd[3] = kp[3];
            vd[0] = vp[0]; vd[1] = vp[1]; vd[2] = vp[2]; vd[3] = vp[3];
        }
        __syncthreads();
        int cnt = SEQ - tile0; if (cnt > 256) cnt = 256;
        int cc = cnt - chunk * 16; if (cc < 0) cc = 0; if (cc > 16) cc = 16;
        const int base = chunk * 16;
        for (int jj = 0; jj < cc; jj += 4) {
            float s[4][4];   // [key][query]
            #pragma unroll
            for (int kx = 0; kx < 4; ++kx) {
                const float4* kr = (const float4*)&Ks[(base + jj + kx) * 20];
                float4 k0 = kr[0], k1 = kr[1], k2 = kr[2], k3 = kr[3];
                #pragma unroll
                for (int qi = 0; qi < 4; ++qi) {
                    float d = q[qi][0].x * k0.x + q[qi][0].y * k0.y + q[qi][0].z * k0.z + q[qi][0].w * k0.w;
                    d += q[qi][1].x * k1.x + q[qi][1].y * k1.y + q[qi][1].z * k1.z + q[qi][1].w * k1.w;
                    d += q[qi][2].x * k2.x + q[qi][2].y * k2.y + q[qi][2].z * k2.z + q[qi][2].w * k2.w;
                    d += q[qi][3].x * k3.x + q[qi][3].y * k3.y + q[qi][3].z * k3.z + q[qi][3].w * k3.w;
                    s[kx][qi] = d;
                }
            }
            float e[4][4];
            #pragma unroll
            for (int qi = 0; qi < 4; ++qi) {
                float gm = fmaxf(fmaxf(s[0][qi], s[1][qi]), fmaxf(s[2][qi], s[3][qi]));
                float nm = fmaxf(m[qi], gm);
                float corr = exp2f(m[qi] - nm);
                float e0 = exp2f(s[0][qi] - nm), e1 = exp2f(s[1][qi] - nm);
                float e2 = exp2f(s[2][qi] - nm), e3 = exp2f(s[3][qi] - nm);
                e[0][qi] = e0; e[1][qi] = e1; e[2][qi] = e2; e[3][qi] = e3;
                l[qi] = fmaf(l[qi], corr, (e0 + e1) + (e2 + e3));
                m[qi] = nm;
                #pragma unroll
                for (int j2 = 0; j2 < 4; ++j2) {
                    acc[qi][j2].x *= corr; acc[qi][j2].y *= corr;
                    acc[qi][j2].z *= corr; acc[qi][j2].w *= corr;
                }
            }
            #pragma unroll
            for (int kx = 0; kx < 4; ++kx) {
                const float4* vr = (const float4*)&Vs[(base + jj + kx) * 20];
                float4 v0 = vr[0], v1 = vr[1], v2 = vr[2], v3 = vr[3];
                #pragma unroll
                for (int qi = 0; qi < 4; ++qi) {
                    float ee = e[kx][qi];
                    acc[qi][0].x = fmaf(ee, v0.x, acc[qi][0].x);
                    acc[qi][0].y = fmaf(ee, v0.y, acc[qi][0].y);
                    acc[qi][0].z = fmaf(ee, v0.z, acc[qi][0].z);
                    acc[qi][0].w = fmaf(ee, v0.w, acc[qi][0].w);
                    acc[qi][1].x = fmaf(ee, v1.x, acc[qi][1].x);
                    acc[qi][1].y = fmaf(ee, v1.y, acc[qi][1].y);
                    acc[qi][1].z = fmaf(ee, v1.z, acc[qi][1].z);
                    acc[qi][1].w = fmaf(ee, v1.w, acc[qi][1].w);
                    acc[qi][2].x = fmaf(ee, v2.x, acc[qi][2].x);
                    acc[qi][2].y = fmaf(ee, v2.y, acc[qi][2].y);
                    acc[qi][2].z = fmaf(ee, v2.z, acc[qi][2].z);
                    acc[qi][2].w = fmaf(ee, v2.w, acc[qi][2].w);
                    acc[qi][3].x = fmaf(ee, v3.x, acc[qi][3].x);
                    acc[qi][3].y = fmaf(ee, v3.y, acc[qi][3].y);
                    acc[qi][3].z = fmaf(ee, v3.z, acc[qi][3].z);
                    acc[qi][3].w = fmaf(ee, v3.w, acc[qi][3].w);
                }
            }
        }
    }
    __syncthreads();   // all waves done with Ks/Vs before reuse as combine buffer

    // merge the 4 chunks that live within each wave (lanes ^16, ^32 share qg)
    #pragma unroll
    for (int mask = 16; mask <= 32; mask <<= 1) {
        #pragma unroll
        for (int qi = 0; qi < 4; ++qi) {
            float m2 = __shfl_xor(m[qi], mask);
            float l2 = __shfl_xor(l[qi], mask);
            float M = fmaxf(m[qi], m2);
            float c1 = exp2f(m[qi] - M), c2 = exp2f(m2 - M);
            l[qi] = l[qi] * c1 + l2 * c2;
            #pragma unroll
            for (int j2 = 0; j2 < 4; ++j2) {
                float4 o = acc[qi][j2];
                float4 o2;
                o2.x = __shfl_xor(o.x, mask);
                o2.y = __shfl_xor(o.y, mask);
                o2.z = __shfl_xor(o.z, mask);
                o2.w = __shfl_xor(o.w, mask);
                o.x = o.x * c1 + o2.x * c2;
                o.y = o.y * c1 + o2.y * c2;
                o.z = o.z * c1 + o2.z * c2;
                o.w = o.w * c1 + o2.w * c2;
                acc[qi][j2] = o;
            }
            m[qi] = M;
        }
    }
    // 4 wave-partials per (qg,qi) -> LDS
    float* pacc = lds;            // 4 waves * 16 qg * 4 qi * 16 = 4096
    float* pm   = lds + 4096;     // 256
    float* pl   = lds + 4352;     // 256
    const int wv = t >> 6;
    if ((t & 63) < 16) {
        #pragma unroll
        for (int qi = 0; qi < 4; ++qi) {
            int slot = (wv * 16 + qg) * 4 + qi;
            float4* dst = (float4*)&pacc[slot * 16];
            dst[0] = acc[qi][0]; dst[1] = acc[qi][1];
            dst[2] = acc[qi][2]; dst[3] = acc[qi][3];
            pm[slot] = m[qi]; pl[slot] = l[qi];
        }
    }
    __syncthreads();
    {
        const int row = t >> 2;           // 0..63
        const int part = t & 3;           // dims part*4..part*4+3
        const int qrow = blockIdx.x * 64 + row;
        if (qrow < SEQ) {
            const int qg2 = row >> 2, qi2 = row & 3;
            float M = -INFINITY;
            #pragma unroll
            for (int w = 0; w < 4; ++w)
                M = fmaxf(M, pm[(w * 16 + qg2) * 4 + qi2]);
            float L = 0.f;
            float4 o = make_float4(0.f, 0.f, 0.f, 0.f);
            #pragma unroll
            for (int w = 0; w < 4; ++w) {
                int slot = (w * 16 + qg2) * 4 + qi2;
                float wgt = exp2f(pm[slot] - M);
                L = fmaf(pl[slot], wgt, L);
                float4 pa = ((const float4*)&pacc[slot * 16])[part];
                o.x = fmaf(pa.x, wgt, o.x); o.y = fmaf(pa.y, wgt, o.y);
                o.z = fmaf(pa.z, wgt, o.z); o.w = fmaf(pa.w, wgt, o.w);
            }
            float inv = 1.f / L;
            o.x *= inv; o.y *= inv; o.z *= inv; o.w *= inv;
            ((float4*)&O[(size_t)qrow * 128 + head * 16])[part] = o;
        }
    }
}

// ---- region + map_fuse + channel-LN stats (fused) ------------------------------
__global__ __launch_bounds__(256) void region_fuse_stats_kernel(
    const float* __restrict__ sup, const float* __restrict__ qry,
    const float* __restrict__ X, float* __restrict__ fused,
    float* __restrict__ MEAN, float* __restrict__ RSTD) {
    __shared__ float key0[2048];   // 16 x 128
    __shared__ float rfac[100];
    const int b = blockIdx.x;
    const int t = threadIdx.x;
    const float* feat = (b < 25) ? (sup + (size_t)b * 12800) : (qry + (size_t)(b - 25) * 12800);
    for (int i = t; i < 2048; i += 256) key0[i] = X[i];
    __syncthreads();
    if (t < 100) {
        float dots[16];
        #pragma unroll
        for (int mm = 0; mm < 16; ++mm) dots[mm] = 0.f;
        float s = 0.f, ss = 0.f;
        for (int c = 0; c < 128; ++c) {
            float f = feat[c * 100 + t];
            s += f; ss += f * f;
            #pragma unroll
            for (int mm = 0; mm < 16; ++mm) dots[mm] += f * key0[mm * 128 + c];
        }
        float mean16 = 0.f;
        #pragma unroll
        for (int mm = 0; mm < 16; ++mm) mean16 += 1.f / (1.f + expf(-dots[mm] * (1.f / 128.f)));
        float r = mean16 * (1.f / 16.f) + 1.f;
        rfac[t] = r;
        float mr = s * (1.f / 128.f);
        float vr = ss * (1.f / 128.f) - mr * mr;
        MEAN[b * 128 + t] = mr * r;
        RSTD[b * 128 + t] = rsqrtf(vr * r * r + 1e-6f);
    }
    __syncthreads();
    for (int i = t; i < 12800; i += 256)
        fused[(size_t)b * 12800 + i] = feat[i] * rfac[i % 100];
}

// ---------------- 3x3 conv, pad 1, 10x10 images --------------------------------
template<int CIN, bool RELU, bool FUSE_LN>
__global__ __launch_bounds__(256) void conv3x3_kernel(
    const float* __restrict__ in, const float* __restrict__ w,
    const float* __restrict__ MEAN, const float* __restrict__ RSTD,
    const float* __restrict__ g, const float* __restrict__ bb,
    float* __restrict__ out) {
    __shared__ float sin_[32 * 144];
    const int b = blockIdx.x;
    const int base_to = blockIdx.y * 8;
    const int t = threadIdx.x;
    const int h = __builtin_amdgcn_readfirstlane(t >> 7);   // wave-uniform
    const int p = t & 127;
    const int py = p / 10, px = p - py * 10;
    const bool active = p < 100;
    float acc[4] = {0.f, 0.f, 0.f, 0.f};
    for (int cb = 0; cb < CIN; cb += 32) {
        if (cb) __syncthreads();
        for (int i = t; i < 32 * 144; i += 256) {
            int c = i / 144, pos = i - c * 144;
            int y = pos / 12 - 1, x = pos % 12 - 1;
            float v = 0.f;
            if ((unsigned)y < 10u && (unsigned)x < 10u) {
                int pp = y * 10 + x;
                float raw = in[(size_t)b * CIN * 100 + (cb + c) * 100 + pp];
                if (FUSE_LN)
                    v = (raw - MEAN[b * 128 + pp]) * RSTD[b * 128 + pp] * g[cb + c] + bb[cb + c];
                else
                    v = raw;
            }
            sin_[i] = v;
        }
        __syncthreads();
        if (active) {
            const float* wbase = w + ((size_t)(base_to + h * 4) * CIN + cb) * 9;
            for (int c = 0; c < 32; ++c) {
                const float* sp = &sin_[c * 144 + py * 12 + px];
                float pix[9];
                #pragma unroll
                for (int k = 0; k < 9; ++k) pix[k] = sp[(k / 3) * 12 + (k % 3)];
                #pragma unroll
                for (int j = 0; j < 4; ++j) {
                    const float* wq = wbase + ((size_t)j * CIN + c) * 9;
                    #pragma unroll
                    for (int k = 0; k < 9; ++k) acc[j] = fmaf(pix[k], wq[k], acc[j]);
                }
            }
        }
    }
    if (active) {
        #pragma unroll
        for (int j = 0; j < 4; ++j) {
            float v = acc[j];
            if (RELU) v = fmaxf(v, 0.f);
            out[(size_t)b * 3200 + (base_to + h * 4 + j) * 100 + p] = v;
        }
    }
}

// ---------------- final pooling -------------------------------------------------
__global__ __launch_bounds__(256) void rfm_out_kernel(
    const float* __restrict__ conv4, const float* __restrict__ fused, float* __restrict__ out) {
    __shared__ float sig[3200];
    __shared__ float sf[12800];
    const int b = blockIdx.x;
    const int t = threadIdx.x;
    for (int i = t; i < 3200; i += 256) sig[i] = 1.f / (1.f + expf(-conv4[(size_t)b * 3200 + i]));
    for (int i = t; i < 12800; i += 256) sf[i] = fused[(size_t)b * 12800 + i];
    __syncthreads();
    for (int o = t; o < 4096; o += 256) {
        int c = o >> 5, tt = o & 31;
        float acc = 0.f;
        for (int p = 0; p < 100; ++p) acc += sig[tt * 100 + p] * sf[c * 100 + p];
        out[(size_t)b * 4096 + o] = acc * 0.01f;
    }
}

extern "C" void kernel_launch(void* const* d_in, const int* in_sizes, int n_in,
                              void* d_out, int out_size, void* d_ws, size_t ws_size,
                              hipStream_t stream) {
    (void)in_sizes; (void)n_in; (void)out_size; (void)ws_size;
    const float* sup    = (const float*)d_in[0];
    const float* qry    = (const float*)d_in[1];
    const float* td     = (const float*)d_in[2];
    const float* ln1_g  = (const float*)d_in[3];
    const float* ln1_b  = (const float*)d_in[4];
    const float* qkv_w  = (const float*)d_in[5];
    const float* qkv_b  = (const float*)d_in[6];
    const float* out_w  = (const float*)d_in[7];
    const float* out_b  = (const float*)d_in[8];
    const float* ln2_g  = (const float*)d_in[9];
    const float* ln2_b  = (const float*)d_in[10];
    const float* mlp_w1 = (const float*)d_in[11];
    const float* mlp_b1 = (const float*)d_in[12];
    const float* mlp_w2 = (const float*)d_in[13];
    const float* mlp_b2 = (const float*)d_in[14];
    const float* rg     = (const float*)d_in[15];
    const float* rb     = (const float*)d_in[16];
    const float* c1     = (const float*)d_in[17];
    const float* c2     = (const float*)d_in[18];
    const float* c3     = (const float*)d_in[19];
    const float* c4     = (const float*)d_in[20];
    float* out = (float*)d_out;

    // buffers padded to 2520 rows so skinny GEMM can read 8-row blocks unguarded
    float* ws   = (float*)d_ws;
    float* X    = ws;                  // 2520*128 = 322560
    float* H    = X + 322560;          // 322560
    float* QKV  = H + 322560;          // 2520*384 = 967680
    float* Obuf = QKV + 967680;        // 322560
    float* MLPH = Obuf + 322560;       // 2520*512 = 1290240
    float* FUSED= MLPH + 1290240;      // 1280000
    float* MEAN = FUSED + 1280000;     // 12800
    float* RSTD = MEAN + 12800;        // 12800
    float* CB1  = RSTD + 12800;        // 320000
    float* CB2  = CB1 + 320000;        // 320000

    const int SG = (SEQ + 7) / 8;      // 315 blocks for skinny GEMMs

    concat_kernel<<<(SEQ * CDIM + 255) / 256, 256, 0, stream>>>(td, sup, X);
    for (int i = 0; i < 2; ++i) {
        ln_row_kernel<<<SEQ, 64, 0, stream>>>(X, H, ln1_g + i * 128, ln1_b + i * 128, 1e-5f);
        sgemm_kernel<384, 8, 0, false><<<SG, 384, 0, stream>>>(
            H, qkv_w + (size_t)i * 128 * 384, qkv_b + i * 384, nullptr, QKV, SEQ, 128);
        attn_kernel<<<dim3(40, 8), 256, 0, stream>>>(QKV, Obuf);
        sgemm_kernel<128, 2, 0, true><<<SG, 512, 0, stream>>>(
            Obuf, out_w + (size_t)i * 128 * 128, out_b + i * 128, X, X, SEQ, 128);
        ln_row_kernel<<<SEQ, 64, 0, stream>>>(X, H, ln2_g + i * 128, ln2_b + i * 128, 1e-5f);
        sgemm_kernel<512, 8, 1, false><<<SG, 512, 0, stream>>>(
            H, mlp_w1 + (size_t)i * 128 * 512, mlp_b1 + i * 512, nullptr, MLPH, SEQ, 128);
        sgemm_kernel<128, 2, 0, true><<<SG, 512, 0, stream>>>(
            MLPH, mlp_w2 + (size_t)i * 512 * 128, mlp_b2 + i * 128, X, X, SEQ, 512);
    }
    region_fuse_stats_kernel<<<100, 256, 0, stream>>>(sup, qry, X, FUSED, MEAN, RSTD);
    conv3x3_kernel<128, true,  true ><<<dim3(100, 4), 256, 0, stream>>>(FUSED, c1, MEAN, RSTD, rg, rb, CB1);
    conv3x3_kernel< 32, true,  false><<<dim3(100, 4), 256, 0, stream>>>(CB1, c2, nullptr, nullptr, nullptr, nullptr, CB2);
    conv3x3_kernel< 32, true,  false><<<dim3(100, 4), 256, 0, stream>>>(CB2, c3, nullptr, nullptr, nullptr, nullptr, CB1);
    conv3x3_kernel< 32, false, false><<<dim3(100, 4), 256, 0, stream>>>(CB1, c4, nullptr, nullptr, nullptr, nullptr, CB2);
    rfm_out_kernel<<<100, 256, 0, stream>>>(CB2, FUSED, out);
}

// Round 5
// 620.782 us; speedup vs baseline: 1.7867x; 1.0208x over previous
//
#include <hip/hip_runtime.h>
#include <math.h>

#define SEQ 2516
#define CDIM 128

__device__ __forceinline__ float gelu_exact(float x) {
    return x * 0.5f * (1.0f + erff(x * 0.7071067811865475f));
}
__device__ __forceinline__ float fexp2(float x) { return __builtin_amdgcn_exp2f(x); }

// ---------------- build x = concat(task_descriptor, support.transpose(0,2,3,1)) ----
__global__ __launch_bounds__(256) void concat_kernel(
    const float* __restrict__ td, const float* __restrict__ sup, float* __restrict__ X) {
    int i = blockIdx.x * 256 + threadIdx.x;
    if (i >= SEQ * CDIM) return;
    int row = i >> 7, c = i & 127;
    if (row < 16) {
        X[i] = td[i];
    } else {
        int r = row - 16;
        int n = r / 100, p = r - n * 100;
        X[i] = sup[n * 12800 + c * 100 + p];
    }
}

// ---------------- row layernorm over last dim (128), 1 wave per row -------------
__global__ __launch_bounds__(64) void ln_row_kernel(
    const float* __restrict__ in, float* __restrict__ out,
    const float* __restrict__ g, const float* __restrict__ b, float eps) {
    const int row = blockIdx.x;
    const int t = threadIdx.x;
    float x0 = in[row * 128 + t];
    float x1 = in[row * 128 + 64 + t];
    float s = x0 + x1;
    for (int off = 32; off > 0; off >>= 1) s += __shfl_down(s, off);
    float mean = __shfl(s, 0) * (1.f / 128.f);
    float d0 = x0 - mean, d1 = x1 - mean;
    float v = d0 * d0 + d1 * d1;
    for (int off = 32; off > 0; off >>= 1) v += __shfl_down(v, off);
    float var = __shfl(v, 0) * (1.f / 128.f);
    float rstd = rsqrtf(var + eps);
    out[row * 128 + t]      = d0 * rstd * g[t] + b[t];
    out[row * 128 + 64 + t] = d1 * rstd * g[t + 64] + b[t + 64];
}

// ---------------- skinny GEMM: 8 M-rows x N cols per block ----------------------
template<int N, int RPT, int ACT, bool RES>
__global__ __launch_bounds__(N * 8 / RPT) void sgemm_kernel(
    const float* __restrict__ A, const float* __restrict__ W,
    const float* __restrict__ bias, const float* __restrict__ R,
    float* __restrict__ C, int M, int K) {
    const int t = threadIdx.x;
    const int c = t % N;
    const int grp = __builtin_amdgcn_readfirstlane(t / N);
    const int r0 = blockIdx.x * 8 + grp * RPT;
    float acc[RPT];
    #pragma unroll
    for (int i = 0; i < RPT; ++i) acc[i] = 0.f;
    #pragma unroll 4
    for (int k0 = 0; k0 < K; k0 += 4) {
        float w0 = W[(size_t)(k0 + 0) * N + c];
        float w1 = W[(size_t)(k0 + 1) * N + c];
        float w2 = W[(size_t)(k0 + 2) * N + c];
        float w3 = W[(size_t)(k0 + 3) * N + c];
        #pragma unroll
        for (int i = 0; i < RPT; ++i) {
            float4 a4 = *(const float4*)&A[(size_t)(r0 + i) * K + k0];
            acc[i] = fmaf(a4.x, w0, acc[i]);
            acc[i] = fmaf(a4.y, w1, acc[i]);
            acc[i] = fmaf(a4.z, w2, acc[i]);
            acc[i] = fmaf(a4.w, w3, acc[i]);
        }
    }
    float bv = bias[c];
    #pragma unroll
    for (int i = 0; i < RPT; ++i) {
        int row = r0 + i;
        if (row < M) {
            float v = acc[i] + bv;
            if (ACT == 1) v = gelu_exact(v);
            if (RES) v += R[(size_t)row * N + c];
            C[(size_t)row * N + c] = v;
        }
    }
}

// ---------------- attention v5: fp32, QB=4, swizzled LDS, Q-tile 32 -------------
// grid (79, 8 heads), block 256 (4 waves). qg = t&7 -> 4 query rows; chunk = t>>3
// (32 chunks x 8 keys per 256-key tile). K/V rows stored at swizzled offset
// r*20 + ((r>>4)&3)*8 so rows 16 apart (simultaneous within a wave) land 8
// banks apart -> worst-case 2-way aliasing (free). Merge: shfl_xor(8,16,32)
// within wave, then LDS across 4 waves.
__device__ __forceinline__ int kvswz(int r) { return r * 20 + ((r >> 4) & 3) * 8; }

__global__ __launch_bounds__(256) void attn_kernel(
    const float* __restrict__ qkv, float* __restrict__ O) {
    __shared__ float lds[10432];
    float* Ks = lds;                       // swizzled, max 255*20+24+16
    float* Vs = lds + 5216;
    const int t = threadIdx.x;
    const int qg = t & 7;
    const int chunk = t >> 3;              // 0..31
    const int head = blockIdx.y;
    const int qbase = blockIdx.x * 32 + qg * 4;
    const float SC = 0.25f * 1.4426950408889634f;   // log2e / sqrt(dh)

    float4 q[4][4];
    #pragma unroll
    for (int i = 0; i < 4; ++i) {
        if (qbase + i < SEQ) {
            const float4* qp = (const float4*)&qkv[(size_t)(qbase + i) * 384 + head * 16];
            #pragma unroll
            for (int j = 0; j < 4; ++j) {
                float4 v = qp[j];
                v.x *= SC; v.y *= SC; v.z *= SC; v.w *= SC;
                q[i][j] = v;
            }
        } else {
            #pragma unroll
            for (int j = 0; j < 4; ++j) q[i][j] = make_float4(0.f, 0.f, 0.f, 0.f);
        }
    }
    float m[4] = {-INFINITY, -INFINITY, -INFINITY, -INFINITY};
    float l[4] = {0.f, 0.f, 0.f, 0.f};
    float4 acc[4][4];
    #pragma unroll
    for (int i = 0; i < 4; ++i)
        #pragma unroll
        for (int j = 0; j < 4; ++j) acc[i][j] = make_float4(0.f, 0.f, 0.f, 0.f);

    for (int tile0 = 0; tile0 < SEQ; tile0 += 256) {
        if (tile0) __syncthreads();
        int j = tile0 + t;
        if (j < SEQ) {
            const float4* kp = (const float4*)&qkv[(size_t)j * 384 + 128 + head * 16];
            const float4* vp = (const float4*)&qkv[(size_t)j * 384 + 256 + head * 16];
            float4* kd = (float4*)&Ks[kvswz(t)];
            float4* vd = (float4*)&Vs[kvswz(t)];
            kd[0] = kp[0]; kd[1] = kp[1]; kd[2] = kp[2]; kd[3] = kp[3];
            vd[0] = vp[0]; vd[1] = vp[1]; vd[2] = vp[2]; vd[3] = vp[3];
        }
        __syncthreads();
        int cnt = SEQ - tile0; if (cnt > 256) cnt = 256;
        int cc = cnt - chunk * 8; if (cc < 0) cc = 0; if (cc > 8) cc = 8;
        const int base = chunk * 8;
        for (int jj = 0; jj < cc; jj += 4) {
            float s[4][4];   // [key][query]
            #pragma unroll
            for (int kx = 0; kx < 4; ++kx) {
                const float4* kr = (const float4*)&Ks[kvswz(base + jj + kx)];
                float4 k0 = kr[0], k1 = kr[1], k2 = kr[2], k3 = kr[3];
                #pragma unroll
                for (int qi = 0; qi < 4; ++qi) {
                    float d = q[qi][0].x * k0.x + q[qi][0].y * k0.y + q[qi][0].z * k0.z + q[qi][0].w * k0.w;
                    d += q[qi][1].x * k1.x + q[qi][1].y * k1.y + q[qi][1].z * k1.z + q[qi][1].w * k1.w;
                    d += q[qi][2].x * k2.x + q[qi][2].y * k2.y + q[qi][2].z * k2.z + q[qi][2].w * k2.w;
                    d += q[qi][3].x * k3.x + q[qi][3].y * k3.y + q[qi][3].z * k3.z + q[qi][3].w * k3.w;
                    s[kx][qi] = d;
                }
            }
            float e[4][4];
            #pragma unroll
            for (int qi = 0; qi < 4; ++qi) {
                float gm = fmaxf(fmaxf(s[0][qi], s[1][qi]), fmaxf(s[2][qi], s[3][qi]));
                float nm = fmaxf(m[qi], gm);
                float corr = fexp2(m[qi] - nm);
                float e0 = fexp2(s[0][qi] - nm), e1 = fexp2(s[1][qi] - nm);
                float e2 = fexp2(s[2][qi] - nm), e3 = fexp2(s[3][qi] - nm);
                e[0][qi] = e0; e[1][qi] = e1; e[2][qi] = e2; e[3][qi] = e3;
                l[qi] = fmaf(l[qi], corr, (e0 + e1) + (e2 + e3));
                m[qi] = nm;
                #pragma unroll
                for (int j2 = 0; j2 < 4; ++j2) {
                    acc[qi][j2].x *= corr; acc[qi][j2].y *= corr;
                    acc[qi][j2].z *= corr; acc[qi][j2].w *= corr;
                }
            }
            #pragma unroll
            for (int kx = 0; kx < 4; ++kx) {
                const float4* vr = (const float4*)&Vs[kvswz(base + jj + kx)];
                float4 v0 = vr[0], v1 = vr[1], v2 = vr[2], v3 = vr[3];
                #pragma unroll
                for (int qi = 0; qi < 4; ++qi) {
                    float ee = e[kx][qi];
                    acc[qi][0].x = fmaf(ee, v0.x, acc[qi][0].x);
                    acc[qi][0].y = fmaf(ee, v0.y, acc[qi][0].y);
                    acc[qi][0].z = fmaf(ee, v0.z, acc[qi][0].z);
                    acc[qi][0].w = fmaf(ee, v0.w, acc[qi][0].w);
                    acc[qi][1].x = fmaf(ee, v1.x, acc[qi][1].x);
                    acc[qi][1].y = fmaf(ee, v1.y, acc[qi][1].y);
                    acc[qi][1].z = fmaf(ee, v1.z, acc[qi][1].z);
                    acc[qi][1].w = fmaf(ee, v1.w, acc[qi][1].w);
                    acc[qi][2].x = fmaf(ee, v2.x, acc[qi][2].x);
                    acc[qi][2].y = fmaf(ee, v2.y, acc[qi][2].y);
                    acc[qi][2].z = fmaf(ee, v2.z, acc[qi][2].z);
                    acc[qi][2].w = fmaf(ee, v2.w, acc[qi][2].w);
                    acc[qi][3].x = fmaf(ee, v3.x, acc[qi][3].x);
                    acc[qi][3].y = fmaf(ee, v3.y, acc[qi][3].y);
                    acc[qi][3].z = fmaf(ee, v3.z, acc[qi][3].z);
                    acc[qi][3].w = fmaf(ee, v3.w, acc[qi][3].w);
                }
            }
        }
    }
    __syncthreads();   // done with Ks/Vs before reuse as combine buffer

    // merge the 4 chunks sharing qg within each wave (masks 8,16,32)
    #pragma unroll
    for (int mask = 8; mask <= 32; mask <<= 1) {
        #pragma unroll
        for (int qi = 0; qi < 4; ++qi) {
            float m2 = __shfl_xor(m[qi], mask);
            float l2 = __shfl_xor(l[qi], mask);
            float M = fmaxf(m[qi], m2);
            float c1 = fexp2(m[qi] - M), c2 = fexp2(m2 - M);
            l[qi] = l[qi] * c1 + l2 * c2;
            #pragma unroll
            for (int j2 = 0; j2 < 4; ++j2) {
                float4 o = acc[qi][j2];
                float4 o2;
                o2.x = __shfl_xor(o.x, mask);
                o2.y = __shfl_xor(o.y, mask);
                o2.z = __shfl_xor(o.z, mask);
                o2.w = __shfl_xor(o.w, mask);
                o.x = o.x * c1 + o2.x * c2;
                o.y = o.y * c1 + o2.y * c2;
                o.z = o.z * c1 + o2.z * c2;
                o.w = o.w * c1 + o2.w * c2;
                acc[qi][j2] = o;
            }
            m[qi] = M;
        }
    }
    // 4 wave-partials per (qg,qi) -> LDS: 4 waves * 8 qg * 4 qi = 128 slots
    float* pacc = lds;            // 128*16 = 2048
    float* pm   = lds + 2048;     // 128
    float* pl   = lds + 2176;     // 128
    const int wv = t >> 6;
    if ((t & 63) < 8) {
        #pragma unroll
        for (int qi = 0; qi < 4; ++qi) {
            int slot = (wv * 8 + qg) * 4 + qi;
            float4* dst = (float4*)&pacc[slot * 16];
            dst[0] = acc[qi][0]; dst[1] = acc[qi][1];
            dst[2] = acc[qi][2]; dst[3] = acc[qi][3];
            pm[slot] = m[qi]; pl[slot] = l[qi];
        }
    }
    __syncthreads();
    if (t < 128) {
        const int row = t >> 2;           // 0..31
        const int part = t & 3;           // dims part*4..part*4+3
        const int qrow = blockIdx.x * 32 + row;
        if (qrow < SEQ) {
            const int qg2 = row >> 2, qi2 = row & 3;
            float M = -INFINITY;
            #pragma unroll
            for (int w = 0; w < 4; ++w)
                M = fmaxf(M, pm[(w * 8 + qg2) * 4 + qi2]);
            float L = 0.f;
            float4 o = make_float4(0.f, 0.f, 0.f, 0.f);
            #pragma unroll
            for (int w = 0; w < 4; ++w) {
                int slot = (w * 8 + qg2) * 4 + qi2;
                float wgt = fexp2(pm[slot] - M);
                L = fmaf(pl[slot], wgt, L);
                float4 pa = ((const float4*)&pacc[slot * 16])[part];
                o.x = fmaf(pa.x, wgt, o.x); o.y = fmaf(pa.y, wgt, o.y);
                o.z = fmaf(pa.z, wgt, o.z); o.w = fmaf(pa.w, wgt, o.w);
            }
            float inv = 1.f / L;
            o.x *= inv; o.y *= inv; o.z *= inv; o.w *= inv;
            ((float4*)&O[(size_t)qrow * 128 + head * 16])[part] = o;
        }
    }
}

// ---- region + map_fuse + channel-LN stats (fused) ------------------------------
__global__ __launch_bounds__(256) void region_fuse_stats_kernel(
    const float* __restrict__ sup, const float* __restrict__ qry,
    const float* __restrict__ X, float* __restrict__ fused,
    float* __restrict__ MEAN, float* __restrict__ RSTD) {
    __shared__ float key0[2048];   // 16 x 128
    __shared__ float rfac[100];
    const int b = blockIdx.x;
    const int t = threadIdx.x;
    const float* feat = (b < 25) ? (sup + (size_t)b * 12800) : (qry + (size_t)(b - 25) * 12800);
    for (int i = t; i < 2048; i += 256) key0[i] = X[i];
    __syncthreads();
    if (t < 100) {
        float dots[16];
        #pragma unroll
        for (int mm = 0; mm < 16; ++mm) dots[mm] = 0.f;
        float s = 0.f, ss = 0.f;
        for (int c = 0; c < 128; ++c) {
            float f = feat[c * 100 + t];
            s += f; ss += f * f;
            #pragma unroll
            for (int mm = 0; mm < 16; ++mm) dots[mm] += f * key0[mm * 128 + c];
        }
        float mean16 = 0.f;
        #pragma unroll
        for (int mm = 0; mm < 16; ++mm) mean16 += 1.f / (1.f + expf(-dots[mm] * (1.f / 128.f)));
        float r = mean16 * (1.f / 16.f) + 1.f;
        rfac[t] = r;
        float mr = s * (1.f / 128.f);
        float vr = ss * (1.f / 128.f) - mr * mr;
        MEAN[b * 128 + t] = mr * r;
        RSTD[b * 128 + t] = rsqrtf(vr * r * r + 1e-6f);
    }
    __syncthreads();
    for (int i = t; i < 12800; i += 256)
        fused[(size_t)b * 12800 + i] = feat[i] * rfac[i % 100];
}

// ---------------- 3x3 conv, pad 1, 10x10 images --------------------------------
template<int CIN, bool RELU, bool FUSE_LN>
__global__ __launch_bounds__(256) void conv3x3_kernel(
    const float* __restrict__ in, const float* __restrict__ w,
    const float* __restrict__ MEAN, const float* __restrict__ RSTD,
    const float* __restrict__ g, const float* __restrict__ bb,
    float* __restrict__ out) {
    __shared__ float sin_[32 * 144];
    const int b = blockIdx.x;
    const int base_to = blockIdx.y * 8;
    const int t = threadIdx.x;
    const int h = __builtin_amdgcn_readfirstlane(t >> 7);   // wave-uniform
    const int p = t & 127;
    const int py = p / 10, px = p - py * 10;
    const bool active = p < 100;
    float acc[4] = {0.f, 0.f, 0.f, 0.f};
    for (int cb = 0; cb < CIN; cb += 32) {
        if (cb) __syncthreads();
        for (int i = t; i < 32 * 144; i += 256) {
            int c = i / 144, pos = i - c * 144;
            int y = pos / 12 - 1, x = pos % 12 - 1;
            float v = 0.f;
            if ((unsigned)y < 10u && (unsigned)x < 10u) {
                int pp = y * 10 + x;
                float raw = in[(size_t)b * CIN * 100 + (cb + c) * 100 + pp];
                if (FUSE_LN)
                    v = (raw - MEAN[b * 128 + pp]) * RSTD[b * 128 + pp] * g[cb + c] + bb[cb + c];
                else
                    v = raw;
            }
            sin_[i] = v;
        }
        __syncthreads();
        if (active) {
            const float* wbase = w + ((size_t)(base_to + h * 4) * CIN + cb) * 9;
            for (int c = 0; c < 32; ++c) {
                const float* sp = &sin_[c * 144 + py * 12 + px];
                float pix[9];
                #pragma unroll
                for (int k = 0; k < 9; ++k) pix[k] = sp[(k / 3) * 12 + (k % 3)];
                #pragma unroll
                for (int j = 0; j < 4; ++j) {
                    const float* wq = wbase + ((size_t)j * CIN + c) * 9;
                    #pragma unroll
                    for (int k = 0; k < 9; ++k) acc[j] = fmaf(pix[k], wq[k], acc[j]);
                }
            }
        }
    }
    if (active) {
        #pragma unroll
        for (int j = 0; j < 4; ++j) {
            float v = acc[j];
            if (RELU) v = fmaxf(v, 0.f);
            out[(size_t)b * 3200 + (base_to + h * 4 + j) * 100 + p] = v;
        }
    }
}

// ---------------- final pooling -------------------------------------------------
__global__ __launch_bounds__(256) void rfm_out_kernel(
    const float* __restrict__ conv4, const float* __restrict__ fused, float* __restrict__ out) {
    __shared__ float sig[3200];
    __shared__ float sf[12800];
    const int b = blockIdx.x;
    const int t = threadIdx.x;
    for (int i = t; i < 3200; i += 256) sig[i] = 1.f / (1.f + expf(-conv4[(size_t)b * 3200 + i]));
    for (int i = t; i < 12800; i += 256) sf[i] = fused[(size_t)b * 12800 + i];
    __syncthreads();
    for (int o = t; o < 4096; o += 256) {
        int c = o >> 5, tt = o & 31;
        float acc = 0.f;
        for (int p = 0; p < 100; ++p) acc += sig[tt * 100 + p] * sf[c * 100 + p];
        out[(size_t)b * 4096 + o] = acc * 0.01f;
    }
}

extern "C" void kernel_launch(void* const* d_in, const int* in_sizes, int n_in,
                              void* d_out, int out_size, void* d_ws, size_t ws_size,
                              hipStream_t stream) {
    (void)in_sizes; (void)n_in; (void)out_size; (void)ws_size;
    const float* sup    = (const float*)d_in[0];
    const float* qry    = (const float*)d_in[1];
    const float* td     = (const float*)d_in[2];
    const float* ln1_g  = (const float*)d_in[3];
    const float* ln1_b  = (const float*)d_in[4];
    const float* qkv_w  = (const float*)d_in[5];
    const float* qkv_b  = (const float*)d_in[6];
    const float* out_w  = (const float*)d_in[7];
    const float* out_b  = (const float*)d_in[8];
    const float* ln2_g  = (const float*)d_in[9];
    const float* ln2_b  = (const float*)d_in[10];
    const float* mlp_w1 = (const float*)d_in[11];
    const float* mlp_b1 = (const float*)d_in[12];
    const float* mlp_w2 = (const float*)d_in[13];
    const float* mlp_b2 = (const float*)d_in[14];
    const float* rg     = (const float*)d_in[15];
    const float* rb     = (const float*)d_in[16];
    const float* c1     = (const float*)d_in[17];
    const float* c2     = (const float*)d_in[18];
    const float* c3     = (const float*)d_in[19];
    const float* c4     = (const float*)d_in[20];
    float* out = (float*)d_out;

    // buffers padded to 2520 rows so skinny GEMM can read 8-row blocks unguarded
    float* ws   = (float*)d_ws;
    float* X    = ws;                  // 2520*128 = 322560
    float* H    = X + 322560;          // 322560
    float* QKV  = H + 322560;          // 2520*384 = 967680
    float* Obuf = QKV + 967680;        // 322560
    float* MLPH = Obuf + 322560;       // 2520*512 = 1290240
    float* FUSED= MLPH + 1290240;      // 1280000
    float* MEAN = FUSED + 1280000;     // 12800
    float* RSTD = MEAN + 12800;        // 12800
    float* CB1  = RSTD + 12800;        // 320000
    float* CB2  = CB1 + 320000;        // 320000

    const int SG = (SEQ + 7) / 8;      // 315 blocks for skinny GEMMs

    concat_kernel<<<(SEQ * CDIM + 255) / 256, 256, 0, stream>>>(td, sup, X);
    for (int i = 0; i < 2; ++i) {
        ln_row_kernel<<<SEQ, 64, 0, stream>>>(X, H, ln1_g + i * 128, ln1_b + i * 128, 1e-5f);
        sgemm_kernel<384, 8, 0, false><<<SG, 384, 0, stream>>>(
            H, qkv_w + (size_t)i * 128 * 384, qkv_b + i * 384, nullptr, QKV, SEQ, 128);
        attn_kernel<<<dim3(79, 8), 256, 0, stream>>>(QKV, Obuf);
        sgemm_kernel<128, 2, 0, true><<<SG, 512, 0, stream>>>(
            Obuf, out_w + (size_t)i * 128 * 128, out_b + i * 128, X, X, SEQ, 128);
        ln_row_kernel<<<SEQ, 64, 0, stream>>>(X, H, ln2_g + i * 128, ln2_b + i * 128, 1e-5f);
        sgemm_kernel<512, 8, 1, false><<<SG, 512, 0, stream>>>(
            H, mlp_w1 + (size_t)i * 128 * 512, mlp_b1 + i * 512, nullptr, MLPH, SEQ, 128);
        sgemm_kernel<128, 2, 0, true><<<SG, 512, 0, stream>>>(
            MLPH, mlp_w2 + (size_t)i * 512 * 128, mlp_b2 + i * 128, X, X, SEQ, 512);
    }
    region_fuse_stats_kernel<<<100, 256, 0, stream>>>(sup, qry, X, FUSED, MEAN, RSTD);
    conv3x3_kernel<128, true,  true ><<<dim3(100, 4), 256, 0, stream>>>(FUSED, c1, MEAN, RSTD, rg, rb, CB1);
    conv3x3_kernel< 32, true,  false><<<dim3(100, 4), 256, 0, stream>>>(CB1, c2, nullptr, nullptr, nullptr, nullptr, CB2);
    conv3x3_kernel< 32, true,  false><<<dim3(100, 4), 256, 0, stream>>>(CB2, c3, nullptr, nullptr, nullptr, nullptr, CB1);
    conv3x3_kernel< 32, false, false><<<dim3(100, 4), 256, 0, stream>>>(CB1, c4, nullptr, nullptr, nullptr, nullptr, CB2);
    rfm_out_kernel<<<100, 256, 0, stream>>>(CB2, FUSED, out);
}